// Round 6
// baseline (332.502 us; speedup 1.0000x reference)
//
#include <hip/hip_runtime.h>
#include <hip/hip_bf16.h>

#define HID 768
#define NHEADS 12
#define HDIM 64
#define SEQ 4096
#define BB 2
#define MTOT (BB * SEQ)   // 8192 rows

typedef __attribute__((ext_vector_type(8))) short bf16x8;
typedef __attribute__((ext_vector_type(16))) float f32x16;

#define LOG2E 1.4426950408889634f

__device__ inline unsigned pack2bf(float a, float b) {
    __hip_bfloat162 h = __float22bfloat162_rn(float2{a, b});
    return *(unsigned*)&h;
}

// ---------------------------------------------------------------------------
// Kernel 0a: cast X fp32 -> bf16. grid 3072, block 256, 8 elems/thread.
// ---------------------------------------------------------------------------
__global__ __launch_bounds__(256) void cast_x_kernel(
    const float* __restrict__ X, __hip_bfloat16* __restrict__ Xb)
{
    const size_t i = ((size_t)blockIdx.x * 256 + threadIdx.x) * 8;
    const float4 x0 = *(const float4*)(X + i);
    const float4 x1 = *(const float4*)(X + i + 4);
    unsigned u[4];
    u[0] = pack2bf(x0.x, x0.y);
    u[1] = pack2bf(x0.z, x0.w);
    u[2] = pack2bf(x1.x, x1.y);
    u[3] = pack2bf(x1.z, x1.w);
    *(uint4*)(Xb + i) = *(uint4*)u;
}

// ---------------------------------------------------------------------------
// Kernel 0b: pack weights: W[in][out] fp32 -> Wt[out(global)][in] bf16.
// z=0..3 selects Wq,Wk,Wv,Wo; Wo at row offset 2304.
// ---------------------------------------------------------------------------
__global__ __launch_bounds__(256) void pack_w_kernel(
    const float* __restrict__ Wq, const float* __restrict__ Wk,
    const float* __restrict__ Wv, const float* __restrict__ Wo,
    __hip_bfloat16* __restrict__ Wt)
{
    const int z = blockIdx.z;
    const float* __restrict__ W = (z == 0) ? Wq : (z == 1) ? Wk : (z == 2) ? Wv : Wo;
    const int in0  = blockIdx.x * 64;
    const int out0 = blockIdx.y * 64;
    const int t = threadIdx.x;

    __shared__ float T[64][65];
#pragma unroll
    for (int i = 0; i < 4; ++i) {
        const int idx = t + 256 * i;
        const int row = idx >> 4;
        const int c4  = (idx & 15) << 2;
        const float4 v = *(const float4*)(W + (size_t)(in0 + row) * HID + out0 + c4);
        T[row][c4 + 0] = v.x; T[row][c4 + 1] = v.y;
        T[row][c4 + 2] = v.z; T[row][c4 + 3] = v.w;
    }
    __syncthreads();

    const int o  = t >> 2;
    const int cb = (t & 3) << 4;
    __hip_bfloat16 tmp[16];
#pragma unroll
    for (int k = 0; k < 16; ++k)
        tmp[k] = __float2bfloat16(T[cb + k][o]);
    __hip_bfloat16* __restrict__ dst =
        Wt + (size_t)(z * HID + out0 + o) * HID + in0 + cb;
    *(uint4*)(dst)     = *(uint4*)(&tmp[0]);
    *(uint4*)(dst + 8) = *(uint4*)(&tmp[8]);
}

// ---------------------------------------------------------------------------
// GEMM staging/compute macros shared by qkv_mfma_kernel and out_mfma_kernel.
// 2-phase global_load_lds double-buffer (round 5; neutral vs reg-staged but
// structurally cleaner: one barrier per K-step, zero staging VGPRs).
// Both-sides 16B-chunk XOR swizzle (rule #21).
// ---------------------------------------------------------------------------
#define GSTAGE(ASB, BSB, BUF, APTR, BPTR, K0) do {                                 \
    _Pragma("unroll")                                                              \
    for (int j_ = 0; j_ < 4; ++j_) {                                               \
        const __hip_bfloat16* ga_ = (APTR) + (size_t)(r0 + 32 * j_) * HID + (K0) + csw; \
        const __hip_bfloat16* gb_ = (BPTR) + (size_t)(r0 + 32 * j_) * HID + (K0) + csw; \
        __builtin_amdgcn_global_load_lds(                                          \
            (const __attribute__((address_space(1))) unsigned*)ga_,                \
            (__attribute__((address_space(3))) unsigned*)(&ASB[BUF][0][0] + (256 * j_ + 64 * w) * 8), 16, 0, 0); \
        __builtin_amdgcn_global_load_lds(                                          \
            (const __attribute__((address_space(1))) unsigned*)gb_,                \
            (__attribute__((address_space(3))) unsigned*)(&BSB[BUF][0][0] + (256 * j_ + 64 * w) * 8), 16, 0, 0); \
    }                                                                              \
} while (0)

#define GTILE(ASB, BSB, BUF) do {                                                  \
    _Pragma("unroll")                                                              \
    for (int kh = 0; kh < 4; ++kh) {                                               \
        const int sc = ((2 * kh + g) ^ (col & 7)) << 3;                            \
        const bf16x8 a0 = *(const bf16x8*)&ASB[BUF][64 * wm + col][sc];            \
        const bf16x8 a1 = *(const bf16x8*)&ASB[BUF][64 * wm + 32 + col][sc];       \
        const bf16x8 b0 = *(const bf16x8*)&BSB[BUF][64 * wn + col][sc];            \
        const bf16x8 b1 = *(const bf16x8*)&BSB[BUF][64 * wn + 32 + col][sc];       \
        acc[0][0] = __builtin_amdgcn_mfma_f32_32x32x16_bf16(a0, b0, acc[0][0], 0, 0, 0); \
        acc[0][1] = __builtin_amdgcn_mfma_f32_32x32x16_bf16(a0, b1, acc[0][1], 0, 0, 0); \
        acc[1][0] = __builtin_amdgcn_mfma_f32_32x32x16_bf16(a1, b0, acc[1][0], 0, 0, 0); \
        acc[1][1] = __builtin_amdgcn_mfma_f32_32x32x16_bf16(a1, b1, acc[1][1], 0, 0, 0); \
    }                                                                              \
} while (0)

// ---------------------------------------------------------------------------
// Kernel 1: fused QKV MFMA GEMM. Q,K -> bf16 [b,h,s,64]; V -> bf16 [b,h,64,s]
// (transposed in-epilogue via LDS). grid (18, 64), block 256, 128x128, BK=64.
// ---------------------------------------------------------------------------
__global__ __launch_bounds__(256) void qkv_mfma_kernel(
    const __hip_bfloat16* __restrict__ Xb, const __hip_bfloat16* __restrict__ Wt,
    const float* __restrict__ bq, const float* __restrict__ bk,
    const float* __restrict__ bv,
    __hip_bfloat16* __restrict__ Qo, __hip_bfloat16* __restrict__ Ko,
    __hip_bfloat16* __restrict__ Vo)
{
    const int nblk = blockIdx.x;          // 0..17
    const int z  = nblk / 6;              // 0=Q,1=K,2=V
    const int f0 = (nblk % 6) * 128;      // feature base within segment
    const int n0 = nblk * 128;            // row base in Wt
    const int m0 = blockIdx.y * 128;

    const float* __restrict__ bias = (z == 0) ? bq : (z == 1) ? bk : bv;

    const int t    = threadIdx.x;
    const int w    = t >> 6;
    const int lane = t & 63;
    const int col  = lane & 31;
    const int g    = lane >> 5;
    const int wm   = w & 1;
    const int wn   = w >> 1;

    __shared__ __hip_bfloat16 smem[4 * 128 * 64];   // A dbuf | B dbuf = 64 KiB
    __hip_bfloat16 (*Asb)[128][64] = (__hip_bfloat16(*)[128][64])smem;
    __hip_bfloat16 (*Bsb)[128][64] = (__hip_bfloat16(*)[128][64])(smem + 2 * 128 * 64);

    const int r0  = t >> 3;                          // 0..31
    const int csw = (((t & 7) ^ (r0 & 7)) << 3);     // swizzled src chunk (elems)

    const __hip_bfloat16* __restrict__ Am = Xb + (size_t)m0 * HID;
    const __hip_bfloat16* __restrict__ Bn = Wt + (size_t)n0 * HID;

    f32x16 acc[2][2];
#pragma unroll
    for (int mt = 0; mt < 2; ++mt)
#pragma unroll
        for (int nt = 0; nt < 2; ++nt)
#pragma unroll
            for (int r = 0; r < 16; ++r) acc[mt][nt][r] = 0.f;

    GSTAGE(Asb, Bsb, 0, Am, Bn, 0);
    __syncthreads();
    for (int k0 = 0; k0 < HID; k0 += 128) {
        GSTAGE(Asb, Bsb, 1, Am, Bn, k0 + 64);
        GTILE(Asb, Bsb, 0);
        __syncthreads();
        if (k0 + 128 < HID) GSTAGE(Asb, Bsb, 0, Am, Bn, k0 + 128);
        GTILE(Asb, Bsb, 1);
        __syncthreads();
    }

    if (z < 2) {
        __hip_bfloat16* __restrict__ Out = (z == 0) ? Qo : Ko;
        const int h = (f0 >> 6) + wn;
#pragma unroll
        for (int mt = 0; mt < 2; ++mt)
#pragma unroll
            for (int nt = 0; nt < 2; ++nt) {
                const int d = 32 * nt + col;
                const float bsv = bias[f0 + 64 * wn + d];
#pragma unroll
                for (int r = 0; r < 16; ++r) {
                    const int m = m0 + 64 * wm + 32 * mt + (r & 3) + 8 * (r >> 2) + 4 * g;
                    const int b = m >> 12;
                    const int s = m & (SEQ - 1);
                    Out[(((size_t)(b * NHEADS + h)) * SEQ + s) * HDIM + d] =
                        __float2bfloat16(acc[mt][nt][r] + bsv);
                }
            }
    } else {
        // V: transpose 128x128 tile via LDS, write Vt [bh][d][s]
        __syncthreads();   // K-loop LDS reads done before overlay
        __hip_bfloat16 (*Ts)[136] = (__hip_bfloat16(*)[136])smem;  // 34816 B < 64 KiB
#pragma unroll
        for (int mt = 0; mt < 2; ++mt)
#pragma unroll
            for (int nt = 0; nt < 2; ++nt) {
                const int nloc = 64 * wn + 32 * nt + col;
                const float bsv = bias[f0 + nloc];
#pragma unroll
                for (int rg = 0; rg < 4; ++rg) {
                    const int mbase = 64 * wm + 32 * mt + 8 * rg + 4 * g;
                    unsigned pu[2];
                    pu[0] = pack2bf(acc[mt][nt][4 * rg + 0] + bsv,
                                    acc[mt][nt][4 * rg + 1] + bsv);
                    pu[1] = pack2bf(acc[mt][nt][4 * rg + 2] + bsv,
                                    acc[mt][nt][4 * rg + 3] + bsv);
                    *(uint2*)&Ts[nloc][mbase] = *(uint2*)pu;
                }
            }
        __syncthreads();
        const int nloc = t >> 1;
        const int half = t & 1;
        const int hh = (f0 >> 6) + (nloc >> 6);
        const int d  = nloc & 63;
        const int bb = m0 >> 12;
        const int s0 = m0 & (SEQ - 1);
        __hip_bfloat16* __restrict__ dst =
            Vo + (((size_t)(bb * NHEADS + hh)) * HDIM + d) * SEQ + s0 + 64 * half;
        const __hip_bfloat16* srcp = &Ts[nloc][64 * half];
#pragma unroll
        for (int j = 0; j < 8; ++j)
            *(uint4*)(dst + 8 * j) = *(const uint4*)(srcp + 8 * j);
    }
}

// ---------------------------------------------------------------------------
// Kernel 2: MFMA flash attention (S^T-swap, K-split). exp2-folded softmax.
// ROUND-6 STRUCTURE CHANGE (occupancy): counters showed the (256,2)/64-q
// version was STALL-bound, not issue-bound (issue-port use ~35%: VALU 58%/2cyc
// + MFMA 30%/8cyc) — with 2 waves/SIMD both waves park at the barrier/lgkm
// together and the SIMD idles. Fix: per-wave q-tile 64 -> 32 rows, acc regs
// 128 -> 64 (St[2]+O[2]), total footprint ~150 -> launch_bounds(256,3) =
// 3 waves/SIMD. Grid x doubles (32 blocks x 128 q). Cost: K/V LDS+HBM reads
// shared by half the q-rows (~1.6x LDS read traffic, FETCH up) — both had
// headroom (LDS ~36% budget, HBM 15% peak).
// Kept: 2-phase global_load_lds dbuf + both-sides XOR swizzle (round 4),
// whole-span madd, permlane32_swap P-transform. No live-across-compute
// staging regs (rounds 1-2 spill lesson); no per-MFMA setprio (round 3).
// Go/no-go: WRITE_SIZE ~50.7 MB (spill check at the tighter 170-reg cap).
// ---------------------------------------------------------------------------
typedef __attribute__((ext_vector_type(2))) unsigned uswap2;

__global__ __launch_bounds__(256, 3) void attn_kernel(
    const __hip_bfloat16* __restrict__ Qb, const __hip_bfloat16* __restrict__ Kb,
    const __hip_bfloat16* __restrict__ Vt, const float* __restrict__ mask,
    __hip_bfloat16* __restrict__ Op, float* __restrict__ lp)
{
    const int bh = blockIdx.y;
    const int b  = bh / NHEADS;
    const int h  = bh - b * NHEADS;
    const int kspan = SEQ / gridDim.z;
    const int kbeg  = blockIdx.z * kspan;

    const int t    = threadIdx.x;
    const int w    = t >> 6;
    const int lane = t & 63;
    const int col  = lane & 31;
    const int g    = lane >> 5;
    const int qw   = blockIdx.x * 128 + 32 * w;    // 32 q-rows per wave

    __shared__ __hip_bfloat16 Ksb[2][64][64];   // 16 KiB, unpadded (DMA dest)
    __shared__ __hip_bfloat16 Vsb[2][64][64];   // 16 KiB
    __shared__ float madd[2048];                // whole kspan, premult log2(e)

    const __hip_bfloat16* __restrict__ Qh = Qb + (size_t)bh * SEQ * HDIM;
    const __hip_bfloat16* __restrict__ Kh = Kb + (size_t)bh * SEQ * HDIM;
    const __hip_bfloat16* __restrict__ Vh = Vt + (size_t)bh * HDIM * SEQ;

    // whole-span additive mask, computed once (visible after prologue barrier)
    for (int j = t; j < kspan; j += 256)
        madd[j] = (1.0f - mask[b * SEQ + kbeg + j]) * (-10000.0f * LOG2E);

    const int r0  = t >> 3;                          // 0..31
    const int csw = (((t & 7) ^ (r0 & 7)) << 3);     // swizzled src chunk (elems)

#define STAGE(BUF, KT) do {                                                        \
    const __hip_bfloat16* gk0_ = Kh + (size_t)((KT) + r0) * HDIM + csw;            \
    const __hip_bfloat16* gk1_ = Kh + (size_t)((KT) + r0 + 32) * HDIM + csw;       \
    const __hip_bfloat16* gv0_ = Vh + (size_t)r0 * SEQ + (KT) + csw;               \
    const __hip_bfloat16* gv1_ = Vh + (size_t)(r0 + 32) * SEQ + (KT) + csw;        \
    __hip_bfloat16* lk_ = &Ksb[BUF][0][0] + w * 512;                               \
    __hip_bfloat16* lv_ = &Vsb[BUF][0][0] + w * 512;                               \
    __builtin_amdgcn_global_load_lds(                                              \
        (const __attribute__((address_space(1))) unsigned*)gk0_,                   \
        (__attribute__((address_space(3))) unsigned*)lk_, 16, 0, 0);               \
    __builtin_amdgcn_global_load_lds(                                              \
        (const __attribute__((address_space(1))) unsigned*)gk1_,                   \
        (__attribute__((address_space(3))) unsigned*)(lk_ + 2048), 16, 0, 0);      \
    __builtin_amdgcn_global_load_lds(                                              \
        (const __attribute__((address_space(1))) unsigned*)gv0_,                   \
        (__attribute__((address_space(3))) unsigned*)lv_, 16, 0, 0);               \
    __builtin_amdgcn_global_load_lds(                                              \
        (const __attribute__((address_space(1))) unsigned*)gv1_,                   \
        (__attribute__((address_space(3))) unsigned*)(lv_ + 2048), 16, 0, 0);      \
} while (0)

    bf16x8 bq[4];
#pragma unroll
    for (int kh = 0; kh < 4; ++kh)
        bq[kh] = *(const bf16x8*)(Qh + (size_t)(qw + col) * HDIM + 16 * kh + 8 * g);

    f32x16 O[2];
    float lac = 0.f;
#pragma unroll
    for (int dt = 0; dt < 2; ++dt)
#pragma unroll
        for (int r = 0; r < 16; ++r) O[dt][r] = 0.f;

    const float kscale = 0.125f * LOG2E;

#define ATTN_TILE(BUF, KT0) do {                                                   \
    f32x16 St[2];                                                                  \
    _Pragma("unroll")                                                              \
    for (int nt = 0; nt < 2; ++nt)                                                 \
        _Pragma("unroll")                                                          \
        for (int r = 0; r < 16; ++r) St[nt][r] = 0.f;                              \
    _Pragma("unroll")                                                              \
    for (int kh = 0; kh < 4; ++kh) {                                               \
        const int sc = ((2 * kh + g) ^ (col & 7)) << 3;                            \
        const bf16x8 ak0 = *(const bf16x8*)&Ksb[BUF][col][sc];                     \
        const bf16x8 ak1 = *(const bf16x8*)&Ksb[BUF][32 + col][sc];                \
        St[0] = __builtin_amdgcn_mfma_f32_32x32x16_bf16(ak0, bq[kh], St[0], 0, 0, 0); \
        St[1] = __builtin_amdgcn_mfma_f32_32x32x16_bf16(ak1, bq[kh], St[1], 0, 0, 0); \
    }                                                                              \
    unsigned g4x[2][4], g4y[2][4];                                                 \
    _Pragma("unroll")                                                              \
    for (int nt = 0; nt < 2; ++nt) {                                               \
        _Pragma("unroll")                                                          \
        for (int b4 = 0; b4 < 4; ++b4) {                                           \
            const float4 mm = *(const float4*)&madd[(KT0) + 32 * nt + 8 * b4 + 4 * g]; \
            const float p0 = __builtin_amdgcn_exp2f(fmaf(St[nt][4 * b4 + 0], kscale, mm.x)); \
            const float p1 = __builtin_amdgcn_exp2f(fmaf(St[nt][4 * b4 + 1], kscale, mm.y)); \
            const float p2 = __builtin_amdgcn_exp2f(fmaf(St[nt][4 * b4 + 2], kscale, mm.z)); \
            const float p3 = __builtin_amdgcn_exp2f(fmaf(St[nt][4 * b4 + 3], kscale, mm.w)); \
            lac += (p0 + p1) + (p2 + p3);                                          \
            g4x[nt][b4] = pack2bf(p0, p1);                                         \
            g4y[nt][b4] = pack2bf(p2, p3);                                         \
        }                                                                          \
    }                                                                              \
    _Pragma("unroll")                                                              \
    for (int kh = 0; kh < 4; ++kh) {                                               \
        const int nt  = kh >> 1;                                                   \
        const int khl = kh & 1;                                                    \
        union { unsigned u[4]; bf16x8 v; } au;                                     \
        ATTN_PTRANS(au, g4x[nt][2 * khl], g4x[nt][2 * khl + 1],                    \
                        g4y[nt][2 * khl], g4y[nt][2 * khl + 1]);                   \
        const int sc = ((2 * kh + g) ^ (col & 7)) << 3;                            \
        const bf16x8 bv0 = *(const bf16x8*)&Vsb[BUF][col][sc];                     \
        const bf16x8 bv1 = *(const bf16x8*)&Vsb[BUF][32 + col][sc];                \
        O[0] = __builtin_amdgcn_mfma_f32_32x32x16_bf16(au.v, bv0, O[0], 0, 0, 0);  \
        O[1] = __builtin_amdgcn_mfma_f32_32x32x16_bf16(au.v, bv1, O[1], 0, 0, 0);  \
    }                                                                              \
} while (0)

#if __has_builtin(__builtin_amdgcn_permlane32_swap)
    // result[0] = l<32 ? lo[l] : hi[l-32]; result[1] = l<32 ? lo[l+32] : hi[l]
    // == exactly A-frag words u0/u2 (verified rounds 1-5, absmax unchanged).
#define ATTN_PTRANS(au, lox, hix, loy, hiy) do {                                   \
    uswap2 sx_ = __builtin_amdgcn_permlane32_swap((lox), (hix), false, false);     \
    uswap2 sy_ = __builtin_amdgcn_permlane32_swap((loy), (hiy), false, false);     \
    au.u[0] = sx_[0]; au.u[1] = sy_[0]; au.u[2] = sx_[1]; au.u[3] = sy_[1];        \
} while (0)
#else
#define ATTN_PTRANS(au, lox, hix, loy, hiy) do {                                   \
    const unsigned sxv_ = g ? (lox) : (hix);                                       \
    const unsigned syv_ = g ? (loy) : (hiy);                                       \
    const unsigned rx_ = (unsigned)__shfl_xor((int)sxv_, 32, 64);                  \
    const unsigned ry_ = (unsigned)__shfl_xor((int)syv_, 32, 64);                  \
    if (g) { au.u[0] = rx_;   au.u[1] = ry_;   au.u[2] = (hix); au.u[3] = (hiy); } \
    else   { au.u[0] = (lox); au.u[1] = (loy); au.u[2] = rx_;   au.u[3] = ry_;  }  \
} while (0)
#endif

    // ---- 2-phase pipelined K-loop (T3-lite), 2 tiles per iteration ----
    STAGE(0, kbeg);
    __syncthreads();                       // prologue drain (vmcnt0 + madd)

    for (int kt0 = 0; kt0 < kspan; kt0 += 128) {
        STAGE(1, kbeg + kt0 + 64);         // always valid: kt0+64 < kspan
        ATTN_TILE(0, kt0);
        __syncthreads();                   // drains my DMA into buf1; all waves done with buf0
        if (kt0 + 128 < kspan) STAGE(0, kbeg + kt0 + 128);
        ATTN_TILE(1, kt0 + 64);
        __syncthreads();                   // drains DMA into buf0; all waves done with buf1
    }
#undef STAGE
#undef ATTN_TILE
#undef ATTN_PTRANS

    const size_t opbase = (size_t)blockIdx.z * ((size_t)MTOT * HID);
    {
        const float l = lac + __shfl_xor(lac, 32, 64);
        if (g == 0)
            lp[((size_t)blockIdx.z * (BB * NHEADS) + bh) * SEQ + qw + col] = l;
#pragma unroll
        for (int dt = 0; dt < 2; ++dt)
#pragma unroll
            for (int r = 0; r < 16; ++r) {
                const int q = qw + (r & 3) + 8 * (r >> 2) + 4 * g;
                const int d = 32 * dt + col;
                Op[opbase + ((size_t)b * SEQ + q) * HID + h * HDIM + d] =
                    __float2bfloat16(O[dt][r]);
            }
    }
}

// ---------------------------------------------------------------------------
// Kernel 2b: combine K-split partials -> Ctx bf16. 8 elems/thread.
// ---------------------------------------------------------------------------
__global__ __launch_bounds__(256) void combine_kernel(
    const __hip_bfloat16* __restrict__ Op, const float* __restrict__ lp,
    __hip_bfloat16* __restrict__ Ctx, int KS)
{
    const size_t i = ((size_t)blockIdx.x * 256 + threadIdx.x) * 8;
    const int n   = (int)(i % HID);
    const int row = (int)(i / HID);
    const int h = n >> 6;
    const int b = row >> 12;
    const int q = row & (SEQ - 1);
    const int bh = b * NHEADS + h;

    float denom = 0.f;
    float o[8] = {};
    for (int kz = 0; kz < KS; ++kz) {
        denom += lp[((size_t)kz * (BB * NHEADS) + bh) * SEQ + q];
        uint4 u = *(const uint4*)(Op + (size_t)kz * ((size_t)MTOT * HID) + i);
        const __hip_bfloat16* e = (const __hip_bfloat16*)&u;
#pragma unroll
        for (int j = 0; j < 8; ++j) o[j] += __bfloat162float(e[j]);
    }
    const float inv = 1.0f / denom;
    unsigned u[4];
#pragma unroll
    for (int j = 0; j < 4; ++j)
        u[j] = pack2bf(o[2 * j] * inv, o[2 * j + 1] * inv);
    *(uint4*)(Ctx + i) = *(uint4*)u;
}

// ---------------------------------------------------------------------------
// Kernel 3: output projection MFMA + bias + residual -> Resid fp32.
// grid (6, 64), block 256. Same 2-phase gload_lds structure as qkv.
// ---------------------------------------------------------------------------
__global__ __launch_bounds__(256) void out_mfma_kernel(
    const __hip_bfloat16* __restrict__ Cb, const __hip_bfloat16* __restrict__ Wto,
    const float* __restrict__ bo, const float* __restrict__ X,
    float* __restrict__ Resid)
{
    const int n0 = blockIdx.x * 128;
    const int m0 = blockIdx.y * 128;

    const int t    = threadIdx.x;
    const int w    = t >> 6;
    const int lane = t & 63;
    const int col  = lane & 31;
    const int g    = lane >> 5;
    const int wm   = w & 1;
    const int wn   = w >> 1;

    __shared__ __hip_bfloat16 smem[4 * 128 * 64];   // A dbuf | B dbuf = 64 KiB
    __hip_bfloat16 (*Asb)[128][64] = (__hip_bfloat16(*)[128][64])smem;
    __hip_bfloat16 (*Bsb)[128][64] = (__hip_bfloat16(*)[128][64])(smem + 2 * 128 * 64);

    const int r0  = t >> 3;
    const int csw = (((t & 7) ^ (r0 & 7)) << 3);

    const __hip_bfloat16* __restrict__ Am = Cb  + (size_t)m0 * HID;
    const __hip_bfloat16* __restrict__ Bn = Wto + (size_t)n0 * HID;

    f32x16 acc[2][2];
#pragma unroll
    for (int mt = 0; mt < 2; ++mt)
#pragma unroll
        for (int nt = 0; nt < 2; ++nt)
#pragma unroll
            for (int r = 0; r < 16; ++r) acc[mt][nt][r] = 0.f;

    GSTAGE(Asb, Bsb, 0, Am, Bn, 0);
    __syncthreads();
    for (int k0 = 0; k0 < HID; k0 += 128) {
        GSTAGE(Asb, Bsb, 1, Am, Bn, k0 + 64);
        GTILE(Asb, Bsb, 0);
        __syncthreads();
        if (k0 + 128 < HID) GSTAGE(Asb, Bsb, 0, Am, Bn, k0 + 128);
        GTILE(Asb, Bsb, 1);
        __syncthreads();
    }

#pragma unroll
    for (int mt = 0; mt < 2; ++mt)
#pragma unroll
        for (int nt = 0; nt < 2; ++nt) {
            const int n = n0 + 64 * wn + 32 * nt + col;
            const float bsv = bo[n];
#pragma unroll
            for (int r = 0; r < 16; ++r) {
                const int m = m0 + 64 * wm + 32 * mt + (r & 3) + 8 * (r >> 2) + 4 * g;
                Resid[(size_t)m * HID + n] = acc[mt][nt][r] + bsv + X[(size_t)m * HID + n];
            }
        }
}

// ---------------------------------------------------------------------------
// Kernel 4: LayerNorm.
// ---------------------------------------------------------------------------
__global__ __launch_bounds__(256) void ln_kernel(
    const float* __restrict__ Rin, const float* __restrict__ gamma,
    const float* __restrict__ beta, float* __restrict__ Out)
{
    const int row = blockIdx.x;
    const int t   = threadIdx.x;
    const float* __restrict__ x = Rin + (size_t)row * HID;

    const float v0 = x[t];
    const float v1 = x[t + 256];
    const float v2 = x[t + 512];
    float s  = v0 + v1 + v2;
    float s2 = v0 * v0 + v1 * v1 + v2 * v2;
#pragma unroll
    for (int off = 32; off; off >>= 1) {
        s  += __shfl_xor(s,  off, 64);
        s2 += __shfl_xor(s2, off, 64);
    }
    __shared__ float rs[4], rs2[4];
    const int w = t >> 6, lane = t & 63;
    if (lane == 0) { rs[w] = s; rs2[w] = s2; }
    __syncthreads();
    const float tot  = rs[0] + rs[1] + rs[2] + rs[3];
    const float tot2 = rs2[0] + rs2[1] + rs2[2] + rs2[3];
    const float mu   = tot * (1.0f / HID);
    const float var  = tot2 * (1.0f / HID) - mu * mu;
    const float rsig = rsqrtf(var + 1e-5f);

    float* __restrict__ y = Out + (size_t)row * HID;
    y[t]       = (v0 - mu) * rsig * gamma[t]       + beta[t];
    y[t + 256] = (v1 - mu) * rsig * gamma[t + 256] + beta[t + 256];
    y[t + 512] = (v2 - mu) * rsig * gamma[t + 512] + beta[t + 512];
}

// ---------------------------------------------------------------------------
extern "C" void kernel_launch(void* const* d_in, const int* in_sizes, int n_in,
                              void* d_out, int out_size, void* d_ws, size_t ws_size,
                              hipStream_t stream)
{
    const float* X     = (const float*)d_in[0];
    const float* mask  = (const float*)d_in[1];
    const float* Wq    = (const float*)d_in[2];
    const float* bq    = (const float*)d_in[3];
    const float* Wk    = (const float*)d_in[4];
    const float* bk    = (const float*)d_in[5];
    const float* Wv    = (const float*)d_in[6];
    const float* bv    = (const float*)d_in[7];
    const float* Wo    = (const float*)d_in[8];
    const float* bo    = (const float*)d_in[9];
    const float* gamma = (const float*)d_in[10];
    const float* beta  = (const float*)d_in[11];
    float* out = (float*)d_out;

    const size_t N = (size_t)MTOT * HID;        // 6,291,456 elements
    const size_t WTE = (size_t)4 * HID * HID;

    char* p = (char*)d_ws;
    __hip_bfloat16* Xb  = (__hip_bfloat16*)p;  p += 2 * N;
    __hip_bfloat16* Wt  = (__hip_bfloat16*)p;  p += 2 * WTE;
    __hip_bfloat16* Qw  = (__hip_bfloat16*)p;  p += 2 * N;
    __hip_bfloat16* Kw  = (__hip_bfloat16*)p;  p += 2 * N;
    __hip_bfloat16* Vtw = (__hip_bfloat16*)p;  p += 2 * N;
    char* opb = p;
    const size_t fixed = (size_t)(opb - (char*)d_ws);

    const size_t lpsz4 = 4 * (size_t)(BB * NHEADS) * SEQ * sizeof(float);
    const int KS = (ws_size >= fixed + 4 * 2 * N + lpsz4) ? 4 : 2;

    __hip_bfloat16* Op  = (__hip_bfloat16*)opb;          // KS*N bf16 partial O
    float* lpt = (float*)(opb + (size_t)KS * 2 * N);     // KS*24*SEQ fp32
    __hip_bfloat16* Ctxb = Xb;      // Xb dead after qkv
    float* Rd = (float*)Kw;         // Kw+Vtw dead after attn: exactly N fp32

    cast_x_kernel<<<(int)(N / 2048), 256, 0, stream>>>(X, Xb);
    pack_w_kernel<<<dim3(12, 12, 4), 256, 0, stream>>>(Wq, Wk, Wv, Wo, Wt);
    qkv_mfma_kernel<<<dim3(18, MTOT / 128), 256, 0, stream>>>(
        Xb, Wt, bq, bk, bv, Qw, Kw, Vtw);
    attn_kernel<<<dim3(SEQ / 128, BB * NHEADS, KS), 256, 0, stream>>>(
        Qw, Kw, Vtw, mask, Op, lpt);
    combine_kernel<<<(int)(N / 2048), 256, 0, stream>>>(Op, lpt, Ctxb, KS);
    out_mfma_kernel<<<dim3(6, MTOT / 128), 256, 0, stream>>>(
        Ctxb, Wt + (size_t)2304 * HID, bo, X, Rd);
    ln_kernel<<<MTOT, 256, 0, stream>>>(Rd, gamma, beta, out);
}

// Round 7
// 324.119 us; speedup vs baseline: 1.0259x; 1.0259x over previous
//
#include <hip/hip_runtime.h>
#include <hip/hip_bf16.h>

#define HID 768
#define NHEADS 12
#define HDIM 64
#define SEQ 4096
#define BB 2
#define MTOT (BB * SEQ)   // 8192 rows

typedef __attribute__((ext_vector_type(8))) short bf16x8;
typedef __attribute__((ext_vector_type(16))) float f32x16;

#define LOG2E 1.4426950408889634f

__device__ inline unsigned pack2bf(float a, float b) {
    __hip_bfloat162 h = __float22bfloat162_rn(float2{a, b});
    return *(unsigned*)&h;
}

// ---------------------------------------------------------------------------
// Kernel 0a: cast X fp32 -> bf16. grid 3072, block 256, 8 elems/thread.
// ---------------------------------------------------------------------------
__global__ __launch_bounds__(256) void cast_x_kernel(
    const float* __restrict__ X, __hip_bfloat16* __restrict__ Xb)
{
    const size_t i = ((size_t)blockIdx.x * 256 + threadIdx.x) * 8;
    const float4 x0 = *(const float4*)(X + i);
    const float4 x1 = *(const float4*)(X + i + 4);
    unsigned u[4];
    u[0] = pack2bf(x0.x, x0.y);
    u[1] = pack2bf(x0.z, x0.w);
    u[2] = pack2bf(x1.x, x1.y);
    u[3] = pack2bf(x1.z, x1.w);
    *(uint4*)(Xb + i) = *(uint4*)u;
}

// ---------------------------------------------------------------------------
// Kernel 0b: pack weights: W[in][out] fp32 -> Wt[out(global)][in] bf16.
// z=0..3 selects Wq,Wk,Wv,Wo; Wo at row offset 2304.
// ---------------------------------------------------------------------------
__global__ __launch_bounds__(256) void pack_w_kernel(
    const float* __restrict__ Wq, const float* __restrict__ Wk,
    const float* __restrict__ Wv, const float* __restrict__ Wo,
    __hip_bfloat16* __restrict__ Wt)
{
    const int z = blockIdx.z;
    const float* __restrict__ W = (z == 0) ? Wq : (z == 1) ? Wk : (z == 2) ? Wv : Wo;
    const int in0  = blockIdx.x * 64;
    const int out0 = blockIdx.y * 64;
    const int t = threadIdx.x;

    __shared__ float T[64][65];
#pragma unroll
    for (int i = 0; i < 4; ++i) {
        const int idx = t + 256 * i;
        const int row = idx >> 4;
        const int c4  = (idx & 15) << 2;
        const float4 v = *(const float4*)(W + (size_t)(in0 + row) * HID + out0 + c4);
        T[row][c4 + 0] = v.x; T[row][c4 + 1] = v.y;
        T[row][c4 + 2] = v.z; T[row][c4 + 3] = v.w;
    }
    __syncthreads();

    const int o  = t >> 2;
    const int cb = (t & 3) << 4;
    __hip_bfloat16 tmp[16];
#pragma unroll
    for (int k = 0; k < 16; ++k)
        tmp[k] = __float2bfloat16(T[cb + k][o]);
    __hip_bfloat16* __restrict__ dst =
        Wt + (size_t)(z * HID + out0 + o) * HID + in0 + cb;
    *(uint4*)(dst)     = *(uint4*)(&tmp[0]);
    *(uint4*)(dst + 8) = *(uint4*)(&tmp[8]);
}

// ---------------------------------------------------------------------------
// GEMM staging/compute macros shared by qkv_mfma_kernel and out_mfma_kernel.
// 2-phase global_load_lds double-buffer; both-sides 16B-chunk XOR swizzle.
// ---------------------------------------------------------------------------
#define GSTAGE(ASB, BSB, BUF, APTR, BPTR, K0) do {                                 \
    _Pragma("unroll")                                                              \
    for (int j_ = 0; j_ < 4; ++j_) {                                               \
        const __hip_bfloat16* ga_ = (APTR) + (size_t)(r0 + 32 * j_) * HID + (K0) + csw; \
        const __hip_bfloat16* gb_ = (BPTR) + (size_t)(r0 + 32 * j_) * HID + (K0) + csw; \
        __builtin_amdgcn_global_load_lds(                                          \
            (const __attribute__((address_space(1))) unsigned*)ga_,                \
            (__attribute__((address_space(3))) unsigned*)(&ASB[BUF][0][0] + (256 * j_ + 64 * w) * 8), 16, 0, 0); \
        __builtin_amdgcn_global_load_lds(                                          \
            (const __attribute__((address_space(1))) unsigned*)gb_,                \
            (__attribute__((address_space(3))) unsigned*)(&BSB[BUF][0][0] + (256 * j_ + 64 * w) * 8), 16, 0, 0); \
    }                                                                              \
} while (0)

#define GTILE(ASB, BSB, BUF) do {                                                  \
    _Pragma("unroll")                                                              \
    for (int kh = 0; kh < 4; ++kh) {                                               \
        const int sc = ((2 * kh + g) ^ (col & 7)) << 3;                            \
        const bf16x8 a0 = *(const bf16x8*)&ASB[BUF][64 * wm + col][sc];            \
        const bf16x8 a1 = *(const bf16x8*)&ASB[BUF][64 * wm + 32 + col][sc];       \
        const bf16x8 b0 = *(const bf16x8*)&BSB[BUF][64 * wn + col][sc];            \
        const bf16x8 b1 = *(const bf16x8*)&BSB[BUF][64 * wn + 32 + col][sc];       \
        acc[0][0] = __builtin_amdgcn_mfma_f32_32x32x16_bf16(a0, b0, acc[0][0], 0, 0, 0); \
        acc[0][1] = __builtin_amdgcn_mfma_f32_32x32x16_bf16(a0, b1, acc[0][1], 0, 0, 0); \
        acc[1][0] = __builtin_amdgcn_mfma_f32_32x32x16_bf16(a1, b0, acc[1][0], 0, 0, 0); \
        acc[1][1] = __builtin_amdgcn_mfma_f32_32x32x16_bf16(a1, b1, acc[1][1], 0, 0, 0); \
    }                                                                              \
} while (0)

// ---------------------------------------------------------------------------
// Kernel 1: fused QKV MFMA GEMM. Q,K -> bf16 [b,h,s,64]; V -> bf16 [b,h,64,s]
// (transposed in-epilogue via LDS). grid (18, 64), block 256, 128x128, BK=64.
// ---------------------------------------------------------------------------
__global__ __launch_bounds__(256) void qkv_mfma_kernel(
    const __hip_bfloat16* __restrict__ Xb, const __hip_bfloat16* __restrict__ Wt,
    const float* __restrict__ bq, const float* __restrict__ bk,
    const float* __restrict__ bv,
    __hip_bfloat16* __restrict__ Qo, __hip_bfloat16* __restrict__ Ko,
    __hip_bfloat16* __restrict__ Vo)
{
    const int nblk = blockIdx.x;          // 0..17
    const int z  = nblk / 6;              // 0=Q,1=K,2=V
    const int f0 = (nblk % 6) * 128;      // feature base within segment
    const int n0 = nblk * 128;            // row base in Wt
    const int m0 = blockIdx.y * 128;

    const float* __restrict__ bias = (z == 0) ? bq : (z == 1) ? bk : bv;

    const int t    = threadIdx.x;
    const int w    = t >> 6;
    const int lane = t & 63;
    const int col  = lane & 31;
    const int g    = lane >> 5;
    const int wm   = w & 1;
    const int wn   = w >> 1;

    __shared__ __hip_bfloat16 smem[4 * 128 * 64];   // A dbuf | B dbuf = 64 KiB
    __hip_bfloat16 (*Asb)[128][64] = (__hip_bfloat16(*)[128][64])smem;
    __hip_bfloat16 (*Bsb)[128][64] = (__hip_bfloat16(*)[128][64])(smem + 2 * 128 * 64);

    const int r0  = t >> 3;                          // 0..31
    const int csw = (((t & 7) ^ (r0 & 7)) << 3);     // swizzled src chunk (elems)

    const __hip_bfloat16* __restrict__ Am = Xb + (size_t)m0 * HID;
    const __hip_bfloat16* __restrict__ Bn = Wt + (size_t)n0 * HID;

    f32x16 acc[2][2];
#pragma unroll
    for (int mt = 0; mt < 2; ++mt)
#pragma unroll
        for (int nt = 0; nt < 2; ++nt)
#pragma unroll
            for (int r = 0; r < 16; ++r) acc[mt][nt][r] = 0.f;

    GSTAGE(Asb, Bsb, 0, Am, Bn, 0);
    __syncthreads();
    for (int k0 = 0; k0 < HID; k0 += 128) {
        GSTAGE(Asb, Bsb, 1, Am, Bn, k0 + 64);
        GTILE(Asb, Bsb, 0);
        __syncthreads();
        if (k0 + 128 < HID) GSTAGE(Asb, Bsb, 0, Am, Bn, k0 + 128);
        GTILE(Asb, Bsb, 1);
        __syncthreads();
    }

    if (z < 2) {
        __hip_bfloat16* __restrict__ Out = (z == 0) ? Qo : Ko;
        const int h = (f0 >> 6) + wn;
#pragma unroll
        for (int mt = 0; mt < 2; ++mt)
#pragma unroll
            for (int nt = 0; nt < 2; ++nt) {
                const int d = 32 * nt + col;
                const float bsv = bias[f0 + 64 * wn + d];
#pragma unroll
                for (int r = 0; r < 16; ++r) {
                    const int m = m0 + 64 * wm + 32 * mt + (r & 3) + 8 * (r >> 2) + 4 * g;
                    const int b = m >> 12;
                    const int s = m & (SEQ - 1);
                    Out[(((size_t)(b * NHEADS + h)) * SEQ + s) * HDIM + d] =
                        __float2bfloat16(acc[mt][nt][r] + bsv);
                }
            }
    } else {
        // V: transpose 128x128 tile via LDS, write Vt [bh][d][s]
        __syncthreads();   // K-loop LDS reads done before overlay
        __hip_bfloat16 (*Ts)[136] = (__hip_bfloat16(*)[136])smem;  // 34816 B < 64 KiB
#pragma unroll
        for (int mt = 0; mt < 2; ++mt)
#pragma unroll
            for (int nt = 0; nt < 2; ++nt) {
                const int nloc = 64 * wn + 32 * nt + col;
                const float bsv = bias[f0 + nloc];
#pragma unroll
                for (int rg = 0; rg < 4; ++rg) {
                    const int mbase = 64 * wm + 32 * mt + 8 * rg + 4 * g;
                    unsigned pu[2];
                    pu[0] = pack2bf(acc[mt][nt][4 * rg + 0] + bsv,
                                    acc[mt][nt][4 * rg + 1] + bsv);
                    pu[1] = pack2bf(acc[mt][nt][4 * rg + 2] + bsv,
                                    acc[mt][nt][4 * rg + 3] + bsv);
                    *(uint2*)&Ts[nloc][mbase] = *(uint2*)pu;
                }
            }
        __syncthreads();
        const int nloc = t >> 1;
        const int half = t & 1;
        const int hh = (f0 >> 6) + (nloc >> 6);
        const int d  = nloc & 63;
        const int bb = m0 >> 12;
        const int s0 = m0 & (SEQ - 1);
        __hip_bfloat16* __restrict__ dst =
            Vo + (((size_t)(bb * NHEADS + hh)) * HDIM + d) * SEQ + s0 + 64 * half;
        const __hip_bfloat16* srcp = &Ts[nloc][64 * half];
#pragma unroll
        for (int j = 0; j < 8; ++j)
            *(uint4*)(dst + 8 * j) = *(const uint4*)(srcp + 8 * j);
    }
}

// ---------------------------------------------------------------------------
// Kernel 2: MFMA flash attention. ROUND-7 (work removal — round-6 showed
// issue-port saturation: VALUBusy 63% @ 3 waves/SIMD, occupancy no longer
// the lever):
//  - KS=1: grid (32, 24) = 768 blocks = EXACTLY 3/CU x 256 CU, one residency
//    wave, no tail. Deletes Op partials (WRITE 50.7 -> ~13 MB), lp, and the
//    whole combine kernel. Normalization fused in-epilogue via per-wave
//    32-float LDS redistribute (q-sums live at lane=q; O-regs need (r,g)-
//    indexed broadcast reads).
//  - madd as MFMA C-operand: madd2[k] = (1-mask)*(-80000) (= madd/kscale);
//    St initialized from madd2 (8 ds_read_b128 into acc regs) replacing
//    32 zero-movs + 8 softmax-loop loads + fmaf->mul. Identical math:
//    (S + madd/kscale)*kscale = S*kscale + madd.
// Kept: 32-q/wave (256,3) shape, 2-phase global_load_lds dbuf + both-sides
// XOR swizzle, permlane32_swap P-transform. No live-across-compute staging
// regs (spill lesson R1-2); no per-MFMA setprio (R3).
// ---------------------------------------------------------------------------
typedef __attribute__((ext_vector_type(2))) unsigned uswap2;

__global__ __launch_bounds__(256, 3) void attn_kernel(
    const __hip_bfloat16* __restrict__ Qb, const __hip_bfloat16* __restrict__ Kb,
    const __hip_bfloat16* __restrict__ Vt, const float* __restrict__ mask,
    __hip_bfloat16* __restrict__ Ctx)
{
    const int bh = blockIdx.y;
    const int b  = bh / NHEADS;
    const int h  = bh - b * NHEADS;

    const int t    = threadIdx.x;
    const int w    = t >> 6;
    const int lane = t & 63;
    const int col  = lane & 31;
    const int g    = lane >> 5;
    const int qw   = blockIdx.x * 128 + 32 * w;    // 32 q-rows per wave

    __shared__ __hip_bfloat16 Ksb[2][64][64];   // 16 KiB, unpadded (DMA dest)
    __shared__ __hip_bfloat16 Vsb[2][64][64];   // 16 KiB
    __shared__ float madd[SEQ];                 // 16 KiB: (1-mask)*(-80000)
    __shared__ float ls[4][32];                 // per-wave 1/l redistribute

    const __hip_bfloat16* __restrict__ Qh = Qb + (size_t)bh * SEQ * HDIM;
    const __hip_bfloat16* __restrict__ Kh = Kb + (size_t)bh * SEQ * HDIM;
    const __hip_bfloat16* __restrict__ Vh = Vt + (size_t)bh * HDIM * SEQ;

    // whole-seq additive mask, premultiplied by 1/kscale (C-operand form)
    for (int j = t; j < SEQ; j += 256)
        madd[j] = (1.0f - mask[b * SEQ + j]) * (-80000.0f);

    const int r0  = t >> 3;                          // 0..31
    const int csw = (((t & 7) ^ (r0 & 7)) << 3);     // swizzled src chunk (elems)

#define STAGE(BUF, KT) do {                                                        \
    const __hip_bfloat16* gk0_ = Kh + (size_t)((KT) + r0) * HDIM + csw;            \
    const __hip_bfloat16* gk1_ = Kh + (size_t)((KT) + r0 + 32) * HDIM + csw;       \
    const __hip_bfloat16* gv0_ = Vh + (size_t)r0 * SEQ + (KT) + csw;               \
    const __hip_bfloat16* gv1_ = Vh + (size_t)(r0 + 32) * SEQ + (KT) + csw;        \
    __hip_bfloat16* lk_ = &Ksb[BUF][0][0] + w * 512;                               \
    __hip_bfloat16* lv_ = &Vsb[BUF][0][0] + w * 512;                               \
    __builtin_amdgcn_global_load_lds(                                              \
        (const __attribute__((address_space(1))) unsigned*)gk0_,                   \
        (__attribute__((address_space(3))) unsigned*)lk_, 16, 0, 0);               \
    __builtin_amdgcn_global_load_lds(                                              \
        (const __attribute__((address_space(1))) unsigned*)gk1_,                   \
        (__attribute__((address_space(3))) unsigned*)(lk_ + 2048), 16, 0, 0);      \
    __builtin_amdgcn_global_load_lds(                                              \
        (const __attribute__((address_space(1))) unsigned*)gv0_,                   \
        (__attribute__((address_space(3))) unsigned*)lv_, 16, 0, 0);               \
    __builtin_amdgcn_global_load_lds(                                              \
        (const __attribute__((address_space(1))) unsigned*)gv1_,                   \
        (__attribute__((address_space(3))) unsigned*)(lv_ + 2048), 16, 0, 0);      \
} while (0)

    bf16x8 bq[4];
#pragma unroll
    for (int kh = 0; kh < 4; ++kh)
        bq[kh] = *(const bf16x8*)(Qh + (size_t)(qw + col) * HDIM + 16 * kh + 8 * g);

    f32x16 O[2];
    float lac = 0.f;
#pragma unroll
    for (int dt = 0; dt < 2; ++dt)
#pragma unroll
        for (int r = 0; r < 16; ++r) O[dt][r] = 0.f;

    const float kscale = 0.125f * LOG2E;

#define ATTN_TILE(BUF, KT0) do {                                                   \
    f32x16 St[2];                                                                  \
    _Pragma("unroll")                                                              \
    for (int nt = 0; nt < 2; ++nt)                                                 \
        _Pragma("unroll")                                                          \
        for (int b4 = 0; b4 < 4; ++b4) {                                           \
            const float4 mm = *(const float4*)&madd[(KT0) + 32 * nt + 8 * b4 + 4 * g]; \
            St[nt][4 * b4 + 0] = mm.x; St[nt][4 * b4 + 1] = mm.y;                  \
            St[nt][4 * b4 + 2] = mm.z; St[nt][4 * b4 + 3] = mm.w;                  \
        }                                                                          \
    _Pragma("unroll")                                                              \
    for (int kh = 0; kh < 4; ++kh) {                                               \
        const int sc = ((2 * kh + g) ^ (col & 7)) << 3;                            \
        const bf16x8 ak0 = *(const bf16x8*)&Ksb[BUF][col][sc];                     \
        const bf16x8 ak1 = *(const bf16x8*)&Ksb[BUF][32 + col][sc];                \
        St[0] = __builtin_amdgcn_mfma_f32_32x32x16_bf16(ak0, bq[kh], St[0], 0, 0, 0); \
        St[1] = __builtin_amdgcn_mfma_f32_32x32x16_bf16(ak1, bq[kh], St[1], 0, 0, 0); \
    }                                                                              \
    unsigned g4x[2][4], g4y[2][4];                                                 \
    _Pragma("unroll")                                                              \
    for (int nt = 0; nt < 2; ++nt) {                                               \
        _Pragma("unroll")                                                          \
        for (int b4 = 0; b4 < 4; ++b4) {                                           \
            const float p0 = __builtin_amdgcn_exp2f(St[nt][4 * b4 + 0] * kscale);  \
            const float p1 = __builtin_amdgcn_exp2f(St[nt][4 * b4 + 1] * kscale);  \
            const float p2 = __builtin_amdgcn_exp2f(St[nt][4 * b4 + 2] * kscale);  \
            const float p3 = __builtin_amdgcn_exp2f(St[nt][4 * b4 + 3] * kscale);  \
            lac += (p0 + p1) + (p2 + p3);                                          \
            g4x[nt][b4] = pack2bf(p0, p1);                                         \
            g4y[nt][b4] = pack2bf(p2, p3);                                         \
        }                                                                          \
    }                                                                              \
    _Pragma("unroll")                                                              \
    for (int kh = 0; kh < 4; ++kh) {                                               \
        const int nt  = kh >> 1;                                                   \
        const int khl = kh & 1;                                                    \
        union { unsigned u[4]; bf16x8 v; } au;                                     \
        ATTN_PTRANS(au, g4x[nt][2 * khl], g4x[nt][2 * khl + 1],                    \
                        g4y[nt][2 * khl], g4y[nt][2 * khl + 1]);                   \
        const int sc = ((2 * kh + g) ^ (col & 7)) << 3;                            \
        const bf16x8 bv0 = *(const bf16x8*)&Vsb[BUF][col][sc];                     \
        const bf16x8 bv1 = *(const bf16x8*)&Vsb[BUF][32 + col][sc];                \
        O[0] = __builtin_amdgcn_mfma_f32_32x32x16_bf16(au.v, bv0, O[0], 0, 0, 0);  \
        O[1] = __builtin_amdgcn_mfma_f32_32x32x16_bf16(au.v, bv1, O[1], 0, 0, 0);  \
    }                                                                              \
} while (0)

#if __has_builtin(__builtin_amdgcn_permlane32_swap)
    // result[0] = l<32 ? lo[l] : hi[l-32]; result[1] = l<32 ? lo[l+32] : hi[l]
    // == exactly A-frag words u0/u2 (verified rounds 1-6, absmax unchanged).
#define ATTN_PTRANS(au, lox, hix, loy, hiy) do {                                   \
    uswap2 sx_ = __builtin_amdgcn_permlane32_swap((lox), (hix), false, false);     \
    uswap2 sy_ = __builtin_amdgcn_permlane32_swap((loy), (hiy), false, false);     \
    au.u[0] = sx_[0]; au.u[1] = sy_[0]; au.u[2] = sx_[1]; au.u[3] = sy_[1];        \
} while (0)
#else
#define ATTN_PTRANS(au, lox, hix, loy, hiy) do {                                   \
    const unsigned sxv_ = g ? (lox) : (hix);                                       \
    const unsigned syv_ = g ? (loy) : (hiy);                                       \
    const unsigned rx_ = (unsigned)__shfl_xor((int)sxv_, 32, 64);                  \
    const unsigned ry_ = (unsigned)__shfl_xor((int)syv_, 32, 64);                  \
    if (g) { au.u[0] = rx_;   au.u[1] = ry_;   au.u[2] = (hix); au.u[3] = (hiy); } \
    else   { au.u[0] = (lox); au.u[1] = (loy); au.u[2] = rx_;   au.u[3] = ry_;  }  \
} while (0)
#endif

    // ---- 2-phase pipelined K-loop over the FULL sequence ----
    STAGE(0, 0);
    __syncthreads();                       // prologue drain (vmcnt0 + madd)

    for (int kt0 = 0; kt0 < SEQ; kt0 += 128) {
        STAGE(1, kt0 + 64);                // always valid: kt0+64 < SEQ
        ATTN_TILE(0, kt0);
        __syncthreads();                   // drains my DMA into buf1; all waves done with buf0
        if (kt0 + 128 < SEQ) STAGE(0, kt0 + 128);
        ATTN_TILE(1, kt0 + 64);
        __syncthreads();                   // drains DMA into buf0; all waves done with buf1
    }
#undef STAGE
#undef ATTN_TILE
#undef ATTN_PTRANS

    // ---- fused normalization + store ----
    {
        const float l = lac + __shfl_xor(lac, 32, 64);   // full row sum, q = qw+col
        if (g == 0) ls[w][col] = 1.0f / l;               // per-wave slot, no x-wave sync
#pragma unroll
        for (int r = 0; r < 16; ++r) {
            const int qloc = (r & 3) + 8 * (r >> 2) + 4 * g;
            const float inv = ls[w][qloc];               // wave-local LDS broadcast
            const int q = qw + qloc;
#pragma unroll
            for (int dt = 0; dt < 2; ++dt) {
                const int d = 32 * dt + col;
                Ctx[((size_t)b * SEQ + q) * HID + h * HDIM + d] =
                    __float2bfloat16(O[dt][r] * inv);
            }
        }
    }
}

// ---------------------------------------------------------------------------
// Kernel 3: output projection MFMA + bias + residual -> Resid fp32.
// grid (6, 64), block 256. Same 2-phase gload_lds structure as qkv.
// ---------------------------------------------------------------------------
__global__ __launch_bounds__(256) void out_mfma_kernel(
    const __hip_bfloat16* __restrict__ Cb, const __hip_bfloat16* __restrict__ Wto,
    const float* __restrict__ bo, const float* __restrict__ X,
    float* __restrict__ Resid)
{
    const int n0 = blockIdx.x * 128;
    const int m0 = blockIdx.y * 128;

    const int t    = threadIdx.x;
    const int w    = t >> 6;
    const int lane = t & 63;
    const int col  = lane & 31;
    const int g    = lane >> 5;
    const int wm   = w & 1;
    const int wn   = w >> 1;

    __shared__ __hip_bfloat16 smem[4 * 128 * 64];   // A dbuf | B dbuf = 64 KiB
    __hip_bfloat16 (*Asb)[128][64] = (__hip_bfloat16(*)[128][64])smem;
    __hip_bfloat16 (*Bsb)[128][64] = (__hip_bfloat16(*)[128][64])(smem + 2 * 128 * 64);

    const int r0  = t >> 3;
    const int csw = (((t & 7) ^ (r0 & 7)) << 3);

    const __hip_bfloat16* __restrict__ Am = Cb  + (size_t)m0 * HID;
    const __hip_bfloat16* __restrict__ Bn = Wto + (size_t)n0 * HID;

    f32x16 acc[2][2];
#pragma unroll
    for (int mt = 0; mt < 2; ++mt)
#pragma unroll
        for (int nt = 0; nt < 2; ++nt)
#pragma unroll
            for (int r = 0; r < 16; ++r) acc[mt][nt][r] = 0.f;

    GSTAGE(Asb, Bsb, 0, Am, Bn, 0);
    __syncthreads();
    for (int k0 = 0; k0 < HID; k0 += 128) {
        GSTAGE(Asb, Bsb, 1, Am, Bn, k0 + 64);
        GTILE(Asb, Bsb, 0);
        __syncthreads();
        if (k0 + 128 < HID) GSTAGE(Asb, Bsb, 0, Am, Bn, k0 + 128);
        GTILE(Asb, Bsb, 1);
        __syncthreads();
    }

#pragma unroll
    for (int mt = 0; mt < 2; ++mt)
#pragma unroll
        for (int nt = 0; nt < 2; ++nt) {
            const int n = n0 + 64 * wn + 32 * nt + col;
            const float bsv = bo[n];
#pragma unroll
            for (int r = 0; r < 16; ++r) {
                const int m = m0 + 64 * wm + 32 * mt + (r & 3) + 8 * (r >> 2) + 4 * g;
                Resid[(size_t)m * HID + n] = acc[mt][nt][r] + bsv + X[(size_t)m * HID + n];
            }
        }
}

// ---------------------------------------------------------------------------
// Kernel 4: LayerNorm.
// ---------------------------------------------------------------------------
__global__ __launch_bounds__(256) void ln_kernel(
    const float* __restrict__ Rin, const float* __restrict__ gamma,
    const float* __restrict__ beta, float* __restrict__ Out)
{
    const int row = blockIdx.x;
    const int t   = threadIdx.x;
    const float* __restrict__ x = Rin + (size_t)row * HID;

    const float v0 = x[t];
    const float v1 = x[t + 256];
    const float v2 = x[t + 512];
    float s  = v0 + v1 + v2;
    float s2 = v0 * v0 + v1 * v1 + v2 * v2;
#pragma unroll
    for (int off = 32; off; off >>= 1) {
        s  += __shfl_xor(s,  off, 64);
        s2 += __shfl_xor(s2, off, 64);
    }
    __shared__ float rs[4], rs2[4];
    const int w = t >> 6, lane = t & 63;
    if (lane == 0) { rs[w] = s; rs2[w] = s2; }
    __syncthreads();
    const float tot  = rs[0] + rs[1] + rs[2] + rs[3];
    const float tot2 = rs2[0] + rs2[1] + rs2[2] + rs2[3];
    const float mu   = tot * (1.0f / HID);
    const float var  = tot2 * (1.0f / HID) - mu * mu;
    const float rsig = rsqrtf(var + 1e-5f);

    float* __restrict__ y = Out + (size_t)row * HID;
    y[t]       = (v0 - mu) * rsig * gamma[t]       + beta[t];
    y[t + 256] = (v1 - mu) * rsig * gamma[t + 256] + beta[t + 256];
    y[t + 512] = (v2 - mu) * rsig * gamma[t + 512] + beta[t + 512];
}

// ---------------------------------------------------------------------------
extern "C" void kernel_launch(void* const* d_in, const int* in_sizes, int n_in,
                              void* d_out, int out_size, void* d_ws, size_t ws_size,
                              hipStream_t stream)
{
    const float* X     = (const float*)d_in[0];
    const float* mask  = (const float*)d_in[1];
    const float* Wq    = (const float*)d_in[2];
    const float* bq    = (const float*)d_in[3];
    const float* Wk    = (const float*)d_in[4];
    const float* bk    = (const float*)d_in[5];
    const float* Wv    = (const float*)d_in[6];
    const float* bv    = (const float*)d_in[7];
    const float* Wo    = (const float*)d_in[8];
    const float* bo    = (const float*)d_in[9];
    const float* gamma = (const float*)d_in[10];
    const float* beta  = (const float*)d_in[11];
    float* out = (float*)d_out;

    const size_t N = (size_t)MTOT * HID;        // 6,291,456 elements
    const size_t WTE = (size_t)4 * HID * HID;

    char* p = (char*)d_ws;
    __hip_bfloat16* Xb  = (__hip_bfloat16*)p;  p += 2 * N;
    __hip_bfloat16* Wt  = (__hip_bfloat16*)p;  p += 2 * WTE;
    __hip_bfloat16* Qw  = (__hip_bfloat16*)p;  p += 2 * N;
    __hip_bfloat16* Kw  = (__hip_bfloat16*)p;  p += 2 * N;
    __hip_bfloat16* Vtw = (__hip_bfloat16*)p;  p += 2 * N;

    __hip_bfloat16* Ctxb = Xb;      // Xb dead after qkv; attn writes Ctx here
    float* Rd = (float*)Kw;         // Kw+Vtw dead after attn: exactly N fp32

    cast_x_kernel<<<(int)(N / 2048), 256, 0, stream>>>(X, Xb);
    pack_w_kernel<<<dim3(12, 12, 4), 256, 0, stream>>>(Wq, Wk, Wv, Wo, Wt);
    qkv_mfma_kernel<<<dim3(18, MTOT / 128), 256, 0, stream>>>(
        Xb, Wt, bq, bk, bv, Qw, Kw, Vtw);
    attn_kernel<<<dim3(SEQ / 128, BB * NHEADS), 256, 0, stream>>>(
        Qw, Kw, Vtw, mask, Ctxb);
    out_mfma_kernel<<<dim3(6, MTOT / 128), 256, 0, stream>>>(
        Ctxb, Wt + (size_t)2304 * HID, bo, X, Rd);
    ln_kernel<<<MTOT, 256, 0, stream>>>(Rd, gamma, beta, out);
}

// Round 8
// 307.087 us; speedup vs baseline: 1.0828x; 1.0555x over previous
//
#include <hip/hip_runtime.h>
#include <hip/hip_bf16.h>

#define HID 768
#define NHEADS 12
#define HDIM 64
#define SEQ 4096
#define BB 2
#define MTOT (BB * SEQ)   // 8192 rows

typedef __attribute__((ext_vector_type(8))) short bf16x8;
typedef __attribute__((ext_vector_type(16))) float f32x16;

#define LOG2E 1.4426950408889634f
#define KSCALE (0.125f * LOG2E)

__device__ inline unsigned pack2bf(float a, float b) {
    __hip_bfloat162 h = __float22bfloat162_rn(float2{a, b});
    return *(unsigned*)&h;
}

// ---------------------------------------------------------------------------
// Kernel 0a: cast X fp32 -> bf16. grid 3072, block 256, 8 elems/thread.
// ---------------------------------------------------------------------------
__global__ __launch_bounds__(256) void cast_x_kernel(
    const float* __restrict__ X, __hip_bfloat16* __restrict__ Xb)
{
    const size_t i = ((size_t)blockIdx.x * 256 + threadIdx.x) * 8;
    const float4 x0 = *(const float4*)(X + i);
    const float4 x1 = *(const float4*)(X + i + 4);
    unsigned u[4];
    u[0] = pack2bf(x0.x, x0.y);
    u[1] = pack2bf(x0.z, x0.w);
    u[2] = pack2bf(x1.x, x1.y);
    u[3] = pack2bf(x1.z, x1.w);
    *(uint4*)(Xb + i) = *(uint4*)u;
}

// ---------------------------------------------------------------------------
// Kernel 0b: pack weights: W[in][out] fp32 -> Wt[out(global)][in] bf16.
// z=0..3 selects Wq,Wk,Wv,Wo; Wo at row offset 2304.
// ---------------------------------------------------------------------------
__global__ __launch_bounds__(256) void pack_w_kernel(
    const float* __restrict__ Wq, const float* __restrict__ Wk,
    const float* __restrict__ Wv, const float* __restrict__ Wo,
    __hip_bfloat16* __restrict__ Wt)
{
    const int z = blockIdx.z;
    const float* __restrict__ W = (z == 0) ? Wq : (z == 1) ? Wk : (z == 2) ? Wv : Wo;
    const int in0  = blockIdx.x * 64;
    const int out0 = blockIdx.y * 64;
    const int t = threadIdx.x;

    __shared__ float T[64][65];
#pragma unroll
    for (int i = 0; i < 4; ++i) {
        const int idx = t + 256 * i;
        const int row = idx >> 4;
        const int c4  = (idx & 15) << 2;
        const float4 v = *(const float4*)(W + (size_t)(in0 + row) * HID + out0 + c4);
        T[row][c4 + 0] = v.x; T[row][c4 + 1] = v.y;
        T[row][c4 + 2] = v.z; T[row][c4 + 3] = v.w;
    }
    __syncthreads();

    const int o  = t >> 2;
    const int cb = (t & 3) << 4;
    __hip_bfloat16 tmp[16];
#pragma unroll
    for (int k = 0; k < 16; ++k)
        tmp[k] = __float2bfloat16(T[cb + k][o]);
    __hip_bfloat16* __restrict__ dst =
        Wt + (size_t)(z * HID + out0 + o) * HID + in0 + cb;
    *(uint4*)(dst)     = *(uint4*)(&tmp[0]);
    *(uint4*)(dst + 8) = *(uint4*)(&tmp[8]);
}

// ---------------------------------------------------------------------------
// GEMM staging/compute macros shared by qkv_mfma_kernel and out_mfma_kernel.
// 2-phase global_load_lds double-buffer; both-sides 16B-chunk XOR swizzle.
// ---------------------------------------------------------------------------
#define GSTAGE(ASB, BSB, BUF, APTR, BPTR, K0) do {                                 \
    _Pragma("unroll")                                                              \
    for (int j_ = 0; j_ < 4; ++j_) {                                               \
        const __hip_bfloat16* ga_ = (APTR) + (size_t)(r0 + 32 * j_) * HID + (K0) + csw; \
        const __hip_bfloat16* gb_ = (BPTR) + (size_t)(r0 + 32 * j_) * HID + (K0) + csw; \
        __builtin_amdgcn_global_load_lds(                                          \
            (const __attribute__((address_space(1))) unsigned*)ga_,                \
            (__attribute__((address_space(3))) unsigned*)(&ASB[BUF][0][0] + (256 * j_ + 64 * w) * 8), 16, 0, 0); \
        __builtin_amdgcn_global_load_lds(                                          \
            (const __attribute__((address_space(1))) unsigned*)gb_,                \
            (__attribute__((address_space(3))) unsigned*)(&BSB[BUF][0][0] + (256 * j_ + 64 * w) * 8), 16, 0, 0); \
    }                                                                              \
} while (0)

#define GTILE(ASB, BSB, BUF) do {                                                  \
    _Pragma("unroll")                                                              \
    for (int kh = 0; kh < 4; ++kh) {                                               \
        const int sc = ((2 * kh + g) ^ (col & 7)) << 3;                            \
        const bf16x8 a0 = *(const bf16x8*)&ASB[BUF][64 * wm + col][sc];            \
        const bf16x8 a1 = *(const bf16x8*)&ASB[BUF][64 * wm + 32 + col][sc];       \
        const bf16x8 b0 = *(const bf16x8*)&BSB[BUF][64 * wn + col][sc];            \
        const bf16x8 b1 = *(const bf16x8*)&BSB[BUF][64 * wn + 32 + col][sc];       \
        acc[0][0] = __builtin_amdgcn_mfma_f32_32x32x16_bf16(a0, b0, acc[0][0], 0, 0, 0); \
        acc[0][1] = __builtin_amdgcn_mfma_f32_32x32x16_bf16(a0, b1, acc[0][1], 0, 0, 0); \
        acc[1][0] = __builtin_amdgcn_mfma_f32_32x32x16_bf16(a1, b0, acc[1][0], 0, 0, 0); \
        acc[1][1] = __builtin_amdgcn_mfma_f32_32x32x16_bf16(a1, b1, acc[1][1], 0, 0, 0); \
    }                                                                              \
} while (0)

// ---------------------------------------------------------------------------
// Kernel 1: fused QKV MFMA GEMM. Q,K -> bf16 [b,h,s,64]; V -> bf16 [b,h,64,s]
// (transposed in-epilogue via LDS). grid (18, 64), block 256, 128x128, BK=64.
// ROUND-8: Q output pre-scaled by KSCALE=0.125*log2(e) — folds the softmax
// scale into the QK^T MFMA so attn's softmax is a bare exp2 (no per-element
// mul). bf16 relative precision unchanged by a constant scale.
// ---------------------------------------------------------------------------
__global__ __launch_bounds__(256) void qkv_mfma_kernel(
    const __hip_bfloat16* __restrict__ Xb, const __hip_bfloat16* __restrict__ Wt,
    const float* __restrict__ bq, const float* __restrict__ bk,
    const float* __restrict__ bv,
    __hip_bfloat16* __restrict__ Qo, __hip_bfloat16* __restrict__ Ko,
    __hip_bfloat16* __restrict__ Vo)
{
    const int nblk = blockIdx.x;          // 0..17
    const int z  = nblk / 6;              // 0=Q,1=K,2=V
    const int f0 = (nblk % 6) * 128;      // feature base within segment
    const int n0 = nblk * 128;            // row base in Wt
    const int m0 = blockIdx.y * 128;

    const float* __restrict__ bias = (z == 0) ? bq : (z == 1) ? bk : bv;

    const int t    = threadIdx.x;
    const int w    = t >> 6;
    const int lane = t & 63;
    const int col  = lane & 31;
    const int g    = lane >> 5;
    const int wm   = w & 1;
    const int wn   = w >> 1;

    __shared__ __hip_bfloat16 smem[4 * 128 * 64];   // A dbuf | B dbuf = 64 KiB
    __hip_bfloat16 (*Asb)[128][64] = (__hip_bfloat16(*)[128][64])smem;
    __hip_bfloat16 (*Bsb)[128][64] = (__hip_bfloat16(*)[128][64])(smem + 2 * 128 * 64);

    const int r0  = t >> 3;                          // 0..31
    const int csw = (((t & 7) ^ (r0 & 7)) << 3);     // swizzled src chunk (elems)

    const __hip_bfloat16* __restrict__ Am = Xb + (size_t)m0 * HID;
    const __hip_bfloat16* __restrict__ Bn = Wt + (size_t)n0 * HID;

    f32x16 acc[2][2];
#pragma unroll
    for (int mt = 0; mt < 2; ++mt)
#pragma unroll
        for (int nt = 0; nt < 2; ++nt)
#pragma unroll
            for (int r = 0; r < 16; ++r) acc[mt][nt][r] = 0.f;

    GSTAGE(Asb, Bsb, 0, Am, Bn, 0);
    __syncthreads();
    for (int k0 = 0; k0 < HID; k0 += 128) {
        GSTAGE(Asb, Bsb, 1, Am, Bn, k0 + 64);
        GTILE(Asb, Bsb, 0);
        __syncthreads();
        if (k0 + 128 < HID) GSTAGE(Asb, Bsb, 0, Am, Bn, k0 + 128);
        GTILE(Asb, Bsb, 1);
        __syncthreads();
    }

    if (z < 2) {
        __hip_bfloat16* __restrict__ Out = (z == 0) ? Qo : Ko;
        const float qscale = (z == 0) ? KSCALE : 1.0f;
        const int h = (f0 >> 6) + wn;
#pragma unroll
        for (int mt = 0; mt < 2; ++mt)
#pragma unroll
            for (int nt = 0; nt < 2; ++nt) {
                const int d = 32 * nt + col;
                const float bsv = bias[f0 + 64 * wn + d];
#pragma unroll
                for (int r = 0; r < 16; ++r) {
                    const int m = m0 + 64 * wm + 32 * mt + (r & 3) + 8 * (r >> 2) + 4 * g;
                    const int b = m >> 12;
                    const int s = m & (SEQ - 1);
                    Out[(((size_t)(b * NHEADS + h)) * SEQ + s) * HDIM + d] =
                        __float2bfloat16((acc[mt][nt][r] + bsv) * qscale);
                }
            }
    } else {
        // V: transpose 128x128 tile via LDS, write Vt [bh][d][s]
        __syncthreads();   // K-loop LDS reads done before overlay
        __hip_bfloat16 (*Ts)[136] = (__hip_bfloat16(*)[136])smem;  // 34816 B < 64 KiB
#pragma unroll
        for (int mt = 0; mt < 2; ++mt)
#pragma unroll
            for (int nt = 0; nt < 2; ++nt) {
                const int nloc = 64 * wn + 32 * nt + col;
                const float bsv = bias[f0 + nloc];
#pragma unroll
                for (int rg = 0; rg < 4; ++rg) {
                    const int mbase = 64 * wm + 32 * mt + 8 * rg + 4 * g;
                    unsigned pu[2];
                    pu[0] = pack2bf(acc[mt][nt][4 * rg + 0] + bsv,
                                    acc[mt][nt][4 * rg + 1] + bsv);
                    pu[1] = pack2bf(acc[mt][nt][4 * rg + 2] + bsv,
                                    acc[mt][nt][4 * rg + 3] + bsv);
                    *(uint2*)&Ts[nloc][mbase] = *(uint2*)pu;
                }
            }
        __syncthreads();
        const int nloc = t >> 1;
        const int half = t & 1;
        const int hh = (f0 >> 6) + (nloc >> 6);
        const int d  = nloc & 63;
        const int bb = m0 >> 12;
        const int s0 = m0 & (SEQ - 1);
        __hip_bfloat16* __restrict__ dst =
            Vo + (((size_t)(bb * NHEADS + hh)) * HDIM + d) * SEQ + s0 + 64 * half;
        const __hip_bfloat16* srcp = &Ts[nloc][64 * half];
#pragma unroll
        for (int j = 0; j < 8; ++j)
            *(uint4*)(dst + 8 * j) = *(const uint4*)(srcp + 8 * j);
    }
}

// ---------------------------------------------------------------------------
// Kernel 2: MFMA flash attention. ROUND-8 (VALU diet — rounds 5-7 showed
// attn pinned at ~147us across 3 structures with VALUBusy 57-63%: the
// softmax VALU/trans stream is the bound, not occupancy/traffic/latency):
//  - Q pre-scaled by KSCALE in qkv; madd = (1-mask)*(-10000*log2e) as MFMA
//    C-operand -> softmax is bare exp2(St). Deletes 32 muls/tile.
//  - Row-sum via ones-B MFMA: Osum = mfma(P_frag, ones, Osum), 4 MFMA/tile
//    on the 30%-busy matrix pipe, replacing 16 VALU adds/tile AND the
//    epilogue shfl+LDS redistribute (each lane holds exactly its rows'
//    sums). Denominator now from the same bf16-rounded P as the numerator.
// Core softmax VALU: 96 -> 48 ops/tile (32 exp2 + 16 cvt_pk).
// Kept: 32-q/wave (256,3), 2-phase global_load_lds dbuf + both-sides XOR
// swizzle, permlane32_swap P-transform, KS=1 fused normalization.
// Go/no-go: WRITE_SIZE stays ~12.3 MB (spill check, +16 acc regs).
// ---------------------------------------------------------------------------
typedef __attribute__((ext_vector_type(2))) unsigned uswap2;

__global__ __launch_bounds__(256, 3) void attn_kernel(
    const __hip_bfloat16* __restrict__ Qb, const __hip_bfloat16* __restrict__ Kb,
    const __hip_bfloat16* __restrict__ Vt, const float* __restrict__ mask,
    __hip_bfloat16* __restrict__ Ctx)
{
    const int bh = blockIdx.y;
    const int b  = bh / NHEADS;
    const int h  = bh - b * NHEADS;

    const int t    = threadIdx.x;
    const int w    = t >> 6;
    const int lane = t & 63;
    const int col  = lane & 31;
    const int g    = lane >> 5;
    const int qw   = blockIdx.x * 128 + 32 * w;    // 32 q-rows per wave

    __shared__ __hip_bfloat16 Ksb[2][64][64];   // 16 KiB, unpadded (DMA dest)
    __shared__ __hip_bfloat16 Vsb[2][64][64];   // 16 KiB
    __shared__ float madd[SEQ];                 // 16 KiB: (1-mask)*(-10000*log2e)

    const __hip_bfloat16* __restrict__ Qh = Qb + (size_t)bh * SEQ * HDIM;
    const __hip_bfloat16* __restrict__ Kh = Kb + (size_t)bh * SEQ * HDIM;
    const __hip_bfloat16* __restrict__ Vh = Vt + (size_t)bh * HDIM * SEQ;

    // whole-seq additive mask in exp2-domain (C-operand form; Q pre-scaled)
    for (int j = t; j < SEQ; j += 256)
        madd[j] = (1.0f - mask[b * SEQ + j]) * (-10000.0f * LOG2E);

    const int r0  = t >> 3;                          // 0..31
    const int csw = (((t & 7) ^ (r0 & 7)) << 3);     // swizzled src chunk (elems)

#define STAGE(BUF, KT) do {                                                        \
    const __hip_bfloat16* gk0_ = Kh + (size_t)((KT) + r0) * HDIM + csw;            \
    const __hip_bfloat16* gk1_ = Kh + (size_t)((KT) + r0 + 32) * HDIM + csw;       \
    const __hip_bfloat16* gv0_ = Vh + (size_t)r0 * SEQ + (KT) + csw;               \
    const __hip_bfloat16* gv1_ = Vh + (size_t)(r0 + 32) * SEQ + (KT) + csw;        \
    __hip_bfloat16* lk_ = &Ksb[BUF][0][0] + w * 512;                               \
    __hip_bfloat16* lv_ = &Vsb[BUF][0][0] + w * 512;                               \
    __builtin_amdgcn_global_load_lds(                                              \
        (const __attribute__((address_space(1))) unsigned*)gk0_,                   \
        (__attribute__((address_space(3))) unsigned*)lk_, 16, 0, 0);               \
    __builtin_amdgcn_global_load_lds(                                              \
        (const __attribute__((address_space(1))) unsigned*)gk1_,                   \
        (__attribute__((address_space(3))) unsigned*)(lk_ + 2048), 16, 0, 0);      \
    __builtin_amdgcn_global_load_lds(                                              \
        (const __attribute__((address_space(1))) unsigned*)gv0_,                   \
        (__attribute__((address_space(3))) unsigned*)lv_, 16, 0, 0);               \
    __builtin_amdgcn_global_load_lds(                                              \
        (const __attribute__((address_space(1))) unsigned*)gv1_,                   \
        (__attribute__((address_space(3))) unsigned*)(lv_ + 2048), 16, 0, 0);      \
} while (0)

    bf16x8 bq[4];
#pragma unroll
    for (int kh = 0; kh < 4; ++kh)
        bq[kh] = *(const bf16x8*)(Qh + (size_t)(qw + col) * HDIM + 16 * kh + 8 * g);

    // ones B-fragment for the row-sum MFMA (bf16 1.0 = 0x3F80)
    union { unsigned u[4]; bf16x8 v; } on_;
    on_.u[0] = 0x3F803F80u; on_.u[1] = 0x3F803F80u;
    on_.u[2] = 0x3F803F80u; on_.u[3] = 0x3F803F80u;
    const bf16x8 vones = on_.v;

    f32x16 O[2], Osum;
#pragma unroll
    for (int dt = 0; dt < 2; ++dt)
#pragma unroll
        for (int r = 0; r < 16; ++r) O[dt][r] = 0.f;
#pragma unroll
    for (int r = 0; r < 16; ++r) Osum[r] = 0.f;

#define ATTN_TILE(BUF, KT0) do {                                                   \
    f32x16 St[2];                                                                  \
    _Pragma("unroll")                                                              \
    for (int nt = 0; nt < 2; ++nt)                                                 \
        _Pragma("unroll")                                                          \
        for (int b4 = 0; b4 < 4; ++b4) {                                           \
            const float4 mm = *(const float4*)&madd[(KT0) + 32 * nt + 8 * b4 + 4 * g]; \
            St[nt][4 * b4 + 0] = mm.x; St[nt][4 * b4 + 1] = mm.y;                  \
            St[nt][4 * b4 + 2] = mm.z; St[nt][4 * b4 + 3] = mm.w;                  \
        }                                                                          \
    _Pragma("unroll")                                                              \
    for (int kh = 0; kh < 4; ++kh) {                                               \
        const int sc = ((2 * kh + g) ^ (col & 7)) << 3;                            \
        const bf16x8 ak0 = *(const bf16x8*)&Ksb[BUF][col][sc];                     \
        const bf16x8 ak1 = *(const bf16x8*)&Ksb[BUF][32 + col][sc];                \
        St[0] = __builtin_amdgcn_mfma_f32_32x32x16_bf16(ak0, bq[kh], St[0], 0, 0, 0); \
        St[1] = __builtin_amdgcn_mfma_f32_32x32x16_bf16(ak1, bq[kh], St[1], 0, 0, 0); \
    }                                                                              \
    unsigned g4x[2][4], g4y[2][4];                                                 \
    _Pragma("unroll")                                                              \
    for (int nt = 0; nt < 2; ++nt) {                                               \
        _Pragma("unroll")                                                          \
        for (int b4 = 0; b4 < 4; ++b4) {                                           \
            const float p0 = __builtin_amdgcn_exp2f(St[nt][4 * b4 + 0]);           \
            const float p1 = __builtin_amdgcn_exp2f(St[nt][4 * b4 + 1]);           \
            const float p2 = __builtin_amdgcn_exp2f(St[nt][4 * b4 + 2]);           \
            const float p3 = __builtin_amdgcn_exp2f(St[nt][4 * b4 + 3]);           \
            g4x[nt][b4] = pack2bf(p0, p1);                                         \
            g4y[nt][b4] = pack2bf(p2, p3);                                         \
        }                                                                          \
    }                                                                              \
    _Pragma("unroll")                                                              \
    for (int kh = 0; kh < 4; ++kh) {                                               \
        const int nt  = kh >> 1;                                                   \
        const int khl = kh & 1;                                                    \
        union { unsigned u[4]; bf16x8 v; } au;                                     \
        ATTN_PTRANS(au, g4x[nt][2 * khl], g4x[nt][2 * khl + 1],                    \
                        g4y[nt][2 * khl], g4y[nt][2 * khl + 1]);                   \
        const int sc = ((2 * kh + g) ^ (col & 7)) << 3;                            \
        const bf16x8 bv0 = *(const bf16x8*)&Vsb[BUF][col][sc];                     \
        const bf16x8 bv1 = *(const bf16x8*)&Vsb[BUF][32 + col][sc];                \
        O[0]  = __builtin_amdgcn_mfma_f32_32x32x16_bf16(au.v, bv0, O[0], 0, 0, 0); \
        O[1]  = __builtin_amdgcn_mfma_f32_32x32x16_bf16(au.v, bv1, O[1], 0, 0, 0); \
        Osum  = __builtin_amdgcn_mfma_f32_32x32x16_bf16(au.v, vones, Osum, 0, 0, 0); \
    }                                                                              \
} while (0)

#if __has_builtin(__builtin_amdgcn_permlane32_swap)
    // result[0] = l<32 ? lo[l] : hi[l-32]; result[1] = l<32 ? lo[l+32] : hi[l]
    // == exactly A-frag words u0/u2 (verified rounds 1-7, absmax unchanged).
#define ATTN_PTRANS(au, lox, hix, loy, hiy) do {                                   \
    uswap2 sx_ = __builtin_amdgcn_permlane32_swap((lox), (hix), false, false);     \
    uswap2 sy_ = __builtin_amdgcn_permlane32_swap((loy), (hiy), false, false);     \
    au.u[0] = sx_[0]; au.u[1] = sy_[0]; au.u[2] = sx_[1]; au.u[3] = sy_[1];        \
} while (0)
#else
#define ATTN_PTRANS(au, lox, hix, loy, hiy) do {                                   \
    const unsigned sxv_ = g ? (lox) : (hix);                                       \
    const unsigned syv_ = g ? (loy) : (hiy);                                       \
    const unsigned rx_ = (unsigned)__shfl_xor((int)sxv_, 32, 64);                  \
    const unsigned ry_ = (unsigned)__shfl_xor((int)syv_, 32, 64);                  \
    if (g) { au.u[0] = rx_;   au.u[1] = ry_;   au.u[2] = (hix); au.u[3] = (hiy); } \
    else   { au.u[0] = (lox); au.u[1] = (loy); au.u[2] = rx_;   au.u[3] = ry_;  }  \
} while (0)
#endif

    // ---- 2-phase pipelined K-loop over the FULL sequence ----
    STAGE(0, 0);
    __syncthreads();                       // prologue drain (vmcnt0 + madd)

    for (int kt0 = 0; kt0 < SEQ; kt0 += 128) {
        STAGE(1, kt0 + 64);                // always valid: kt0+64 < SEQ
        ATTN_TILE(0, kt0);
        __syncthreads();                   // drains my DMA into buf1; all waves done with buf0
        if (kt0 + 128 < SEQ) STAGE(0, kt0 + 128);
        ATTN_TILE(1, kt0 + 64);
        __syncthreads();                   // drains DMA into buf0; all waves done with buf1
    }
#undef STAGE
#undef ATTN_TILE
#undef ATTN_PTRANS

    // ---- fused normalization + store (Osum[r] = row sum for this lane's rows) ----
#pragma unroll
    for (int r = 0; r < 16; ++r) {
        const int qloc = (r & 3) + 8 * (r >> 2) + 4 * g;
        const float inv = 1.0f / Osum[r];
        const int q = qw + qloc;
#pragma unroll
        for (int dt = 0; dt < 2; ++dt) {
            const int d = 32 * dt + col;
            Ctx[((size_t)b * SEQ + q) * HID + h * HDIM + d] =
                __float2bfloat16(O[dt][r] * inv);
        }
    }
}

// ---------------------------------------------------------------------------
// Kernel 3: output projection MFMA + bias + residual -> Resid fp32.
// grid (6, 64), block 256. Same 2-phase gload_lds structure as qkv.
// ---------------------------------------------------------------------------
__global__ __launch_bounds__(256) void out_mfma_kernel(
    const __hip_bfloat16* __restrict__ Cb, const __hip_bfloat16* __restrict__ Wto,
    const float* __restrict__ bo, const float* __restrict__ X,
    float* __restrict__ Resid)
{
    const int n0 = blockIdx.x * 128;
    const int m0 = blockIdx.y * 128;

    const int t    = threadIdx.x;
    const int w    = t >> 6;
    const int lane = t & 63;
    const int col  = lane & 31;
    const int g    = lane >> 5;
    const int wm   = w & 1;
    const int wn   = w >> 1;

    __shared__ __hip_bfloat16 smem[4 * 128 * 64];   // A dbuf | B dbuf = 64 KiB
    __hip_bfloat16 (*Asb)[128][64] = (__hip_bfloat16(*)[128][64])smem;
    __hip_bfloat16 (*Bsb)[128][64] = (__hip_bfloat16(*)[128][64])(smem + 2 * 128 * 64);

    const int r0  = t >> 3;
    const int csw = (((t & 7) ^ (r0 & 7)) << 3);

    const __hip_bfloat16* __restrict__ Am = Cb  + (size_t)m0 * HID;
    const __hip_bfloat16* __restrict__ Bn = Wto + (size_t)n0 * HID;

    f32x16 acc[2][2];
#pragma unroll
    for (int mt = 0; mt < 2; ++mt)
#pragma unroll
        for (int nt = 0; nt < 2; ++nt)
#pragma unroll
            for (int r = 0; r < 16; ++r) acc[mt][nt][r] = 0.f;

    GSTAGE(Asb, Bsb, 0, Am, Bn, 0);
    __syncthreads();
    for (int k0 = 0; k0 < HID; k0 += 128) {
        GSTAGE(Asb, Bsb, 1, Am, Bn, k0 + 64);
        GTILE(Asb, Bsb, 0);
        __syncthreads();
        if (k0 + 128 < HID) GSTAGE(Asb, Bsb, 0, Am, Bn, k0 + 128);
        GTILE(Asb, Bsb, 1);
        __syncthreads();
    }

#pragma unroll
    for (int mt = 0; mt < 2; ++mt)
#pragma unroll
        for (int nt = 0; nt < 2; ++nt) {
            const int n = n0 + 64 * wn + 32 * nt + col;
            const float bsv = bo[n];
#pragma unroll
            for (int r = 0; r < 16; ++r) {
                const int m = m0 + 64 * wm + 32 * mt + (r & 3) + 8 * (r >> 2) + 4 * g;
                Resid[(size_t)m * HID + n] = acc[mt][nt][r] + bsv + X[(size_t)m * HID + n];
            }
        }
}

// ---------------------------------------------------------------------------
// Kernel 4: LayerNorm.
// ---------------------------------------------------------------------------
__global__ __launch_bounds__(256) void ln_kernel(
    const float* __restrict__ Rin, const float* __restrict__ gamma,
    const float* __restrict__ beta, float* __restrict__ Out)
{
    const int row = blockIdx.x;
    const int t   = threadIdx.x;
    const float* __restrict__ x = Rin + (size_t)row * HID;

    const float v0 = x[t];
    const float v1 = x[t + 256];
    const float v2 = x[t + 512];
    float s  = v0 + v1 + v2;
    float s2 = v0 * v0 + v1 * v1 + v2 * v2;
#pragma unroll
    for (int off = 32; off; off >>= 1) {
        s  += __shfl_xor(s,  off, 64);
        s2 += __shfl_xor(s2, off, 64);
    }
    __shared__ float rs[4], rs2[4];
    const int w = t >> 6, lane = t & 63;
    if (lane == 0) { rs[w] = s; rs2[w] = s2; }
    __syncthreads();
    const float tot  = rs[0] + rs[1] + rs[2] + rs[3];
    const float tot2 = rs2[0] + rs2[1] + rs2[2] + rs2[3];
    const float mu   = tot * (1.0f / HID);
    const float var  = tot2 * (1.0f / HID) - mu * mu;
    const float rsig = rsqrtf(var + 1e-5f);

    float* __restrict__ y = Out + (size_t)row * HID;
    y[t]       = (v0 - mu) * rsig * gamma[t]       + beta[t];
    y[t + 256] = (v1 - mu) * rsig * gamma[t + 256] + beta[t + 256];
    y[t + 512] = (v2 - mu) * rsig * gamma[t + 512] + beta[t + 512];
}

// ---------------------------------------------------------------------------
extern "C" void kernel_launch(void* const* d_in, const int* in_sizes, int n_in,
                              void* d_out, int out_size, void* d_ws, size_t ws_size,
                              hipStream_t stream)
{
    const float* X     = (const float*)d_in[0];
    const float* mask  = (const float*)d_in[1];
    const float* Wq    = (const float*)d_in[2];
    const float* bq    = (const float*)d_in[3];
    const float* Wk    = (const float*)d_in[4];
    const float* bk    = (const float*)d_in[5];
    const float* Wv    = (const float*)d_in[6];
    const float* bv    = (const float*)d_in[7];
    const float* Wo    = (const float*)d_in[8];
    const float* bo    = (const float*)d_in[9];
    const float* gamma = (const float*)d_in[10];
    const float* beta  = (const float*)d_in[11];
    float* out = (float*)d_out;

    const size_t N = (size_t)MTOT * HID;        // 6,291,456 elements
    const size_t WTE = (size_t)4 * HID * HID;

    char* p = (char*)d_ws;
    __hip_bfloat16* Xb  = (__hip_bfloat16*)p;  p += 2 * N;
    __hip_bfloat16* Wt  = (__hip_bfloat16*)p;  p += 2 * WTE;
    __hip_bfloat16* Qw  = (__hip_bfloat16*)p;  p += 2 * N;
    __hip_bfloat16* Kw  = (__hip_bfloat16*)p;  p += 2 * N;
    __hip_bfloat16* Vtw = (__hip_bfloat16*)p;  p += 2 * N;

    __hip_bfloat16* Ctxb = Xb;      // Xb dead after qkv; attn writes Ctx here
    float* Rd = (float*)Kw;         // Kw+Vtw dead after attn: exactly N fp32

    cast_x_kernel<<<(int)(N / 2048), 256, 0, stream>>>(X, Xb);
    pack_w_kernel<<<dim3(12, 12, 4), 256, 0, stream>>>(Wq, Wk, Wv, Wo, Wt);
    qkv_mfma_kernel<<<dim3(18, MTOT / 128), 256, 0, stream>>>(
        Xb, Wt, bq, bk, bv, Qw, Kw, Vtw);
    attn_kernel<<<dim3(SEQ / 128, BB * NHEADS), 256, 0, stream>>>(
        Qw, Kw, Vtw, mask, Ctxb);
    out_mfma_kernel<<<dim3(6, MTOT / 128), 256, 0, stream>>>(
        Ctxb, Wt + (size_t)2304 * HID, bo, X, Rd);
    ln_kernel<<<MTOT, 256, 0, stream>>>(Rd, gamma, beta, out);
}

// Round 9
// 301.539 us; speedup vs baseline: 1.1027x; 1.0184x over previous
//
#include <hip/hip_runtime.h>
#include <hip/hip_bf16.h>

#define HID 768
#define NHEADS 12
#define HDIM 64
#define SEQ 4096
#define BB 2
#define MTOT (BB * SEQ)   // 8192 rows

typedef __attribute__((ext_vector_type(8))) short bf16x8;
typedef __attribute__((ext_vector_type(16))) float f32x16;

#define LOG2E 1.4426950408889634f
#define KSCALE (0.125f * LOG2E)

__device__ inline unsigned pack2bf(float a, float b) {
    __hip_bfloat162 h = __float22bfloat162_rn(float2{a, b});
    return *(unsigned*)&h;
}

// ---------------------------------------------------------------------------
// Kernel 0a: cast X fp32 -> bf16. grid 3072, block 256, 8 elems/thread.
// ---------------------------------------------------------------------------
__global__ __launch_bounds__(256) void cast_x_kernel(
    const float* __restrict__ X, __hip_bfloat16* __restrict__ Xb)
{
    const size_t i = ((size_t)blockIdx.x * 256 + threadIdx.x) * 8;
    const float4 x0 = *(const float4*)(X + i);
    const float4 x1 = *(const float4*)(X + i + 4);
    unsigned u[4];
    u[0] = pack2bf(x0.x, x0.y);
    u[1] = pack2bf(x0.z, x0.w);
    u[2] = pack2bf(x1.x, x1.y);
    u[3] = pack2bf(x1.z, x1.w);
    *(uint4*)(Xb + i) = *(uint4*)u;
}

// ---------------------------------------------------------------------------
// Kernel 0b: pack weights: W[in][out] fp32 -> Wt[out(global)][in] bf16.
// z=0..3 selects Wq,Wk,Wv,Wo; Wo at row offset 2304.
// ---------------------------------------------------------------------------
__global__ __launch_bounds__(256) void pack_w_kernel(
    const float* __restrict__ Wq, const float* __restrict__ Wk,
    const float* __restrict__ Wv, const float* __restrict__ Wo,
    __hip_bfloat16* __restrict__ Wt)
{
    const int z = blockIdx.z;
    const float* __restrict__ W = (z == 0) ? Wq : (z == 1) ? Wk : (z == 2) ? Wv : Wo;
    const int in0  = blockIdx.x * 64;
    const int out0 = blockIdx.y * 64;
    const int t = threadIdx.x;

    __shared__ float T[64][65];
#pragma unroll
    for (int i = 0; i < 4; ++i) {
        const int idx = t + 256 * i;
        const int row = idx >> 4;
        const int c4  = (idx & 15) << 2;
        const float4 v = *(const float4*)(W + (size_t)(in0 + row) * HID + out0 + c4);
        T[row][c4 + 0] = v.x; T[row][c4 + 1] = v.y;
        T[row][c4 + 2] = v.z; T[row][c4 + 3] = v.w;
    }
    __syncthreads();

    const int o  = t >> 2;
    const int cb = (t & 3) << 4;
    __hip_bfloat16 tmp[16];
#pragma unroll
    for (int k = 0; k < 16; ++k)
        tmp[k] = __float2bfloat16(T[cb + k][o]);
    __hip_bfloat16* __restrict__ dst =
        Wt + (size_t)(z * HID + out0 + o) * HID + in0 + cb;
    *(uint4*)(dst)     = *(uint4*)(&tmp[0]);
    *(uint4*)(dst + 8) = *(uint4*)(&tmp[8]);
}

// ---------------------------------------------------------------------------
// GEMM staging/compute macros shared by qkv_mfma_kernel and out_mfma_kernel.
// 2-phase global_load_lds double-buffer; both-sides 16B-chunk XOR swizzle.
// ---------------------------------------------------------------------------
#define GSTAGE(ASB, BSB, BUF, APTR, BPTR, K0) do {                                 \
    _Pragma("unroll")                                                              \
    for (int j_ = 0; j_ < 4; ++j_) {                                               \
        const __hip_bfloat16* ga_ = (APTR) + (size_t)(r0 + 32 * j_) * HID + (K0) + csw; \
        const __hip_bfloat16* gb_ = (BPTR) + (size_t)(r0 + 32 * j_) * HID + (K0) + csw; \
        __builtin_amdgcn_global_load_lds(                                          \
            (const __attribute__((address_space(1))) unsigned*)ga_,                \
            (__attribute__((address_space(3))) unsigned*)(&ASB[BUF][0][0] + (256 * j_ + 64 * w) * 8), 16, 0, 0); \
        __builtin_amdgcn_global_load_lds(                                          \
            (const __attribute__((address_space(1))) unsigned*)gb_,                \
            (__attribute__((address_space(3))) unsigned*)(&BSB[BUF][0][0] + (256 * j_ + 64 * w) * 8), 16, 0, 0); \
    }                                                                              \
} while (0)

#define GTILE(ASB, BSB, BUF) do {                                                  \
    _Pragma("unroll")                                                              \
    for (int kh = 0; kh < 4; ++kh) {                                               \
        const int sc = ((2 * kh + g) ^ (col & 7)) << 3;                            \
        const bf16x8 a0 = *(const bf16x8*)&ASB[BUF][64 * wm + col][sc];            \
        const bf16x8 a1 = *(const bf16x8*)&ASB[BUF][64 * wm + 32 + col][sc];       \
        const bf16x8 b0 = *(const bf16x8*)&BSB[BUF][64 * wn + col][sc];            \
        const bf16x8 b1 = *(const bf16x8*)&BSB[BUF][64 * wn + 32 + col][sc];       \
        acc[0][0] = __builtin_amdgcn_mfma_f32_32x32x16_bf16(a0, b0, acc[0][0], 0, 0, 0); \
        acc[0][1] = __builtin_amdgcn_mfma_f32_32x32x16_bf16(a0, b1, acc[0][1], 0, 0, 0); \
        acc[1][0] = __builtin_amdgcn_mfma_f32_32x32x16_bf16(a1, b0, acc[1][0], 0, 0, 0); \
        acc[1][1] = __builtin_amdgcn_mfma_f32_32x32x16_bf16(a1, b1, acc[1][1], 0, 0, 0); \
    }                                                                              \
} while (0)

// ---------------------------------------------------------------------------
// Kernel 1: fused QKV MFMA GEMM. Q,K -> bf16 [b,h,s,64]; V -> bf16 [b,h,64,s]
// (transposed in-epilogue via LDS). grid (18, 64), block 256, 128x128, BK=64.
// Q output pre-scaled by KSCALE=0.125*log2(e) (round 8) — folds the softmax
// scale into the QK^T MFMA so attn's softmax is a bare exp2.
// ---------------------------------------------------------------------------
__global__ __launch_bounds__(256) void qkv_mfma_kernel(
    const __hip_bfloat16* __restrict__ Xb, const __hip_bfloat16* __restrict__ Wt,
    const float* __restrict__ bq, const float* __restrict__ bk,
    const float* __restrict__ bv,
    __hip_bfloat16* __restrict__ Qo, __hip_bfloat16* __restrict__ Ko,
    __hip_bfloat16* __restrict__ Vo)
{
    const int nblk = blockIdx.x;          // 0..17
    const int z  = nblk / 6;              // 0=Q,1=K,2=V
    const int f0 = (nblk % 6) * 128;      // feature base within segment
    const int n0 = nblk * 128;            // row base in Wt
    const int m0 = blockIdx.y * 128;

    const float* __restrict__ bias = (z == 0) ? bq : (z == 1) ? bk : bv;

    const int t    = threadIdx.x;
    const int w    = t >> 6;
    const int lane = t & 63;
    const int col  = lane & 31;
    const int g    = lane >> 5;
    const int wm   = w & 1;
    const int wn   = w >> 1;

    __shared__ __hip_bfloat16 smem[4 * 128 * 64];   // A dbuf | B dbuf = 64 KiB
    __hip_bfloat16 (*Asb)[128][64] = (__hip_bfloat16(*)[128][64])smem;
    __hip_bfloat16 (*Bsb)[128][64] = (__hip_bfloat16(*)[128][64])(smem + 2 * 128 * 64);

    const int r0  = t >> 3;                          // 0..31
    const int csw = (((t & 7) ^ (r0 & 7)) << 3);     // swizzled src chunk (elems)

    const __hip_bfloat16* __restrict__ Am = Xb + (size_t)m0 * HID;
    const __hip_bfloat16* __restrict__ Bn = Wt + (size_t)n0 * HID;

    f32x16 acc[2][2];
#pragma unroll
    for (int mt = 0; mt < 2; ++mt)
#pragma unroll
        for (int nt = 0; nt < 2; ++nt)
#pragma unroll
            for (int r = 0; r < 16; ++r) acc[mt][nt][r] = 0.f;

    GSTAGE(Asb, Bsb, 0, Am, Bn, 0);
    __syncthreads();
    for (int k0 = 0; k0 < HID; k0 += 128) {
        GSTAGE(Asb, Bsb, 1, Am, Bn, k0 + 64);
        GTILE(Asb, Bsb, 0);
        __syncthreads();
        if (k0 + 128 < HID) GSTAGE(Asb, Bsb, 0, Am, Bn, k0 + 128);
        GTILE(Asb, Bsb, 1);
        __syncthreads();
    }

    if (z < 2) {
        __hip_bfloat16* __restrict__ Out = (z == 0) ? Qo : Ko;
        const float qscale = (z == 0) ? KSCALE : 1.0f;
        const int h = (f0 >> 6) + wn;
#pragma unroll
        for (int mt = 0; mt < 2; ++mt)
#pragma unroll
            for (int nt = 0; nt < 2; ++nt) {
                const int d = 32 * nt + col;
                const float bsv = bias[f0 + 64 * wn + d];
#pragma unroll
                for (int r = 0; r < 16; ++r) {
                    const int m = m0 + 64 * wm + 32 * mt + (r & 3) + 8 * (r >> 2) + 4 * g;
                    const int b = m >> 12;
                    const int s = m & (SEQ - 1);
                    Out[(((size_t)(b * NHEADS + h)) * SEQ + s) * HDIM + d] =
                        __float2bfloat16((acc[mt][nt][r] + bsv) * qscale);
                }
            }
    } else {
        // V: transpose 128x128 tile via LDS, write Vt [bh][d][s]
        __syncthreads();   // K-loop LDS reads done before overlay
        __hip_bfloat16 (*Ts)[136] = (__hip_bfloat16(*)[136])smem;  // 34816 B < 64 KiB
#pragma unroll
        for (int mt = 0; mt < 2; ++mt)
#pragma unroll
            for (int nt = 0; nt < 2; ++nt) {
                const int nloc = 64 * wn + 32 * nt + col;
                const float bsv = bias[f0 + nloc];
#pragma unroll
                for (int rg = 0; rg < 4; ++rg) {
                    const int mbase = 64 * wm + 32 * mt + 8 * rg + 4 * g;
                    unsigned pu[2];
                    pu[0] = pack2bf(acc[mt][nt][4 * rg + 0] + bsv,
                                    acc[mt][nt][4 * rg + 1] + bsv);
                    pu[1] = pack2bf(acc[mt][nt][4 * rg + 2] + bsv,
                                    acc[mt][nt][4 * rg + 3] + bsv);
                    *(uint2*)&Ts[nloc][mbase] = *(uint2*)pu;
                }
            }
        __syncthreads();
        const int nloc = t >> 1;
        const int half = t & 1;
        const int hh = (f0 >> 6) + (nloc >> 6);
        const int d  = nloc & 63;
        const int bb = m0 >> 12;
        const int s0 = m0 & (SEQ - 1);
        __hip_bfloat16* __restrict__ dst =
            Vo + (((size_t)(bb * NHEADS + hh)) * HDIM + d) * SEQ + s0 + 64 * half;
        const __hip_bfloat16* srcp = &Ts[nloc][64 * half];
#pragma unroll
        for (int j = 0; j < 8; ++j)
            *(uint4*)(dst + 8 * j) = *(const uint4*)(srcp + 8 * j);
    }
}

// ---------------------------------------------------------------------------
// Kernel 2: MFMA flash attention. ROUND-9 (P-transform annihilation):
// QK^T's St k-layout (k_hat = c + 8*b4 + 4*g) vs PV A-frag layout
// (k = 8*g + j) differ by EXACTLY a swap of bits 2<->3 of the k index.
// Since QK's A-operand rows ARE the K-tile LDS rows, stage global K row
// sigma(r) (bits 2,3 swapped) into LDS row r. Then each lane's own packed
// P registers are already PV's A-fragment in order:
//   au = {g4x[nt][2khl], g4y[nt][2khl], g4x[nt][2khl+1], g4y[nt][2khl+1]}
// -> ALL 16 permlane32_swap/tile deleted (zero-instruction transform,
// m173/HK pre-permuted-source pattern). Consistency: each MFMA's 16-k set
// unchanged (sigma permutes within 16-blocks) -> St bitwise identical;
// V k-index is its COLUMNS (unpermuted) -> PV reads unchanged; madd C-init
// re-indexed to kt0+32nt+16*(b4>>1)+8g+4*(b4&1); Osum (B=ones) unaffected.
// Kept from rounds 4-8: 32-q/wave (256,3), 2-phase global_load_lds dbuf +
// both-sides XOR chunk swizzle, KSCALE folded into Q, madd as MFMA
// C-operand (bare-exp2 softmax), row-sum via ones-B MFMA, KS=1 fused
// normalization. No live-across-compute staging regs (R1-2 spill lesson);
// no per-MFMA setprio (R3 fence lesson).
// ---------------------------------------------------------------------------
__global__ __launch_bounds__(256, 3) void attn_kernel(
    const __hip_bfloat16* __restrict__ Qb, const __hip_bfloat16* __restrict__ Kb,
    const __hip_bfloat16* __restrict__ Vt, const float* __restrict__ mask,
    __hip_bfloat16* __restrict__ Ctx)
{
    const int bh = blockIdx.y;
    const int b  = bh / NHEADS;
    const int h  = bh - b * NHEADS;

    const int t    = threadIdx.x;
    const int w    = t >> 6;
    const int lane = t & 63;
    const int col  = lane & 31;
    const int g    = lane >> 5;
    const int qw   = blockIdx.x * 128 + 32 * w;    // 32 q-rows per wave

    __shared__ __hip_bfloat16 Ksb[2][64][64];   // 16 KiB, unpadded (DMA dest)
    __shared__ __hip_bfloat16 Vsb[2][64][64];   // 16 KiB
    __shared__ float madd[SEQ];                 // 16 KiB: (1-mask)*(-10000*log2e)

    const __hip_bfloat16* __restrict__ Qh = Qb + (size_t)bh * SEQ * HDIM;
    const __hip_bfloat16* __restrict__ Kh = Kb + (size_t)bh * SEQ * HDIM;
    const __hip_bfloat16* __restrict__ Vh = Vt + (size_t)bh * HDIM * SEQ;

    // whole-seq additive mask in exp2-domain (C-operand form; Q pre-scaled)
    for (int j = t; j < SEQ; j += 256)
        madd[j] = (1.0f - mask[b * SEQ + j]) * (-10000.0f * LOG2E);

    const int r0  = t >> 3;                          // 0..31 (LDS dest row)
    const int csw = (((t & 7) ^ (r0 & 7)) << 3);     // swizzled src chunk (elems)
    // sigma(r0): swap bits 2,3 — K-row permutation absorbing the P-transform
    const int r0s = (r0 & 0x13) | ((r0 & 4) << 1) | ((r0 & 8) >> 1);

#define STAGE(BUF, KT) do {                                                        \
    const __hip_bfloat16* gk0_ = Kh + (size_t)((KT) + r0s) * HDIM + csw;           \
    const __hip_bfloat16* gk1_ = Kh + (size_t)((KT) + r0s + 32) * HDIM + csw;      \
    const __hip_bfloat16* gv0_ = Vh + (size_t)r0 * SEQ + (KT) + csw;               \
    const __hip_bfloat16* gv1_ = Vh + (size_t)(r0 + 32) * SEQ + (KT) + csw;        \
    __hip_bfloat16* lk_ = &Ksb[BUF][0][0] + w * 512;                               \
    __hip_bfloat16* lv_ = &Vsb[BUF][0][0] + w * 512;                               \
    __builtin_amdgcn_global_load_lds(                                              \
        (const __attribute__((address_space(1))) unsigned*)gk0_,                   \
        (__attribute__((address_space(3))) unsigned*)lk_, 16, 0, 0);               \
    __builtin_amdgcn_global_load_lds(                                              \
        (const __attribute__((address_space(1))) unsigned*)gk1_,                   \
        (__attribute__((address_space(3))) unsigned*)(lk_ + 2048), 16, 0, 0);      \
    __builtin_amdgcn_global_load_lds(                                              \
        (const __attribute__((address_space(1))) unsigned*)gv0_,                   \
        (__attribute__((address_space(3))) unsigned*)lv_, 16, 0, 0);               \
    __builtin_amdgcn_global_load_lds(                                              \
        (const __attribute__((address_space(1))) unsigned*)gv1_,                   \
        (__attribute__((address_space(3))) unsigned*)(lv_ + 2048), 16, 0, 0);      \
} while (0)

    bf16x8 bq[4];
#pragma unroll
    for (int kh = 0; kh < 4; ++kh)
        bq[kh] = *(const bf16x8*)(Qh + (size_t)(qw + col) * HDIM + 16 * kh + 8 * g);

    // ones B-fragment for the row-sum MFMA (bf16 1.0 = 0x3F80)
    union { unsigned u[4]; bf16x8 v; } on_;
    on_.u[0] = 0x3F803F80u; on_.u[1] = 0x3F803F80u;
    on_.u[2] = 0x3F803F80u; on_.u[3] = 0x3F803F80u;
    const bf16x8 vones = on_.v;

    f32x16 O[2], Osum;
#pragma unroll
    for (int dt = 0; dt < 2; ++dt)
#pragma unroll
        for (int r = 0; r < 16; ++r) O[dt][r] = 0.f;
#pragma unroll
    for (int r = 0; r < 16; ++r) Osum[r] = 0.f;

#define ATTN_TILE(BUF, KT0) do {                                                   \
    f32x16 St[2];                                                                  \
    /* C-init from madd at the sigma-permuted k each reg now holds:         */     \
    /* global k = KT0 + 32nt + 16*(b4>>1) + 8g + 4*(b4&1) + c               */     \
    _Pragma("unroll")                                                              \
    for (int nt = 0; nt < 2; ++nt)                                                 \
        _Pragma("unroll")                                                          \
        for (int b4 = 0; b4 < 4; ++b4) {                                           \
            const float4 mm = *(const float4*)&madd[(KT0) + 32 * nt                \
                + 16 * (b4 >> 1) + 8 * g + 4 * (b4 & 1)];                          \
            St[nt][4 * b4 + 0] = mm.x; St[nt][4 * b4 + 1] = mm.y;                  \
            St[nt][4 * b4 + 2] = mm.z; St[nt][4 * b4 + 3] = mm.w;                  \
        }                                                                          \
    _Pragma("unroll")                                                              \
    for (int kh = 0; kh < 4; ++kh) {                                               \
        const int sc = ((2 * kh + g) ^ (col & 7)) << 3;                            \
        const bf16x8 ak0 = *(const bf16x8*)&Ksb[BUF][col][sc];                     \
        const bf16x8 ak1 = *(const bf16x8*)&Ksb[BUF][32 + col][sc];                \
        St[0] = __builtin_amdgcn_mfma_f32_32x32x16_bf16(ak0, bq[kh], St[0], 0, 0, 0); \
        St[1] = __builtin_amdgcn_mfma_f32_32x32x16_bf16(ak1, bq[kh], St[1], 0, 0, 0); \
    }                                                                              \
    unsigned g4x[2][4], g4y[2][4];                                                 \
    _Pragma("unroll")                                                              \
    for (int nt = 0; nt < 2; ++nt) {                                               \
        _Pragma("unroll")                                                          \
        for (int b4 = 0; b4 < 4; ++b4) {                                           \
            const float p0 = __builtin_amdgcn_exp2f(St[nt][4 * b4 + 0]);           \
            const float p1 = __builtin_amdgcn_exp2f(St[nt][4 * b4 + 1]);           \
            const float p2 = __builtin_amdgcn_exp2f(St[nt][4 * b4 + 2]);           \
            const float p3 = __builtin_amdgcn_exp2f(St[nt][4 * b4 + 3]);           \
            g4x[nt][b4] = pack2bf(p0, p1);                                         \
            g4y[nt][b4] = pack2bf(p2, p3);                                         \
        }                                                                          \
    }                                                                              \
    _Pragma("unroll")                                                              \
    for (int kh = 0; kh < 4; ++kh) {                                               \
        const int nt  = kh >> 1;                                                   \
        const int khl = kh & 1;                                                    \
        union { unsigned u[4]; bf16x8 v; } au;                                     \
        /* direct A-frag assembly — no cross-lane ops (sigma staged it) */         \
        au.u[0] = g4x[nt][2 * khl];     au.u[1] = g4y[nt][2 * khl];                \
        au.u[2] = g4x[nt][2 * khl + 1]; au.u[3] = g4y[nt][2 * khl + 1];            \
        const int sc = ((2 * kh + g) ^ (col & 7)) << 3;                            \
        const bf16x8 bv0 = *(const bf16x8*)&Vsb[BUF][col][sc];                     \
        const bf16x8 bv1 = *(const bf16x8*)&Vsb[BUF][32 + col][sc];                \
        O[0]  = __builtin_amdgcn_mfma_f32_32x32x16_bf16(au.v, bv0, O[0], 0, 0, 0); \
        O[1]  = __builtin_amdgcn_mfma_f32_32x32x16_bf16(au.v, bv1, O[1], 0, 0, 0); \
        Osum  = __builtin_amdgcn_mfma_f32_32x32x16_bf16(au.v, vones, Osum, 0, 0, 0); \
    }                                                                              \
} while (0)

    // ---- 2-phase pipelined K-loop over the FULL sequence ----
    STAGE(0, 0);
    __syncthreads();                       // prologue drain (vmcnt0 + madd)

    for (int kt0 = 0; kt0 < SEQ; kt0 += 128) {
        STAGE(1, kt0 + 64);                // always valid: kt0+64 < SEQ
        ATTN_TILE(0, kt0);
        __syncthreads();                   // drains my DMA into buf1; all waves done with buf0
        if (kt0 + 128 < SEQ) STAGE(0, kt0 + 128);
        ATTN_TILE(1, kt0 + 64);
        __syncthreads();                   // drains DMA into buf0; all waves done with buf1
    }
#undef STAGE
#undef ATTN_TILE

    // ---- fused normalization + store (Osum[r] = row sum for this lane's rows) ----
#pragma unroll
    for (int r = 0; r < 16; ++r) {
        const int qloc = (r & 3) + 8 * (r >> 2) + 4 * g;
        const float inv = 1.0f / Osum[r];
        const int q = qw + qloc;
#pragma unroll
        for (int dt = 0; dt < 2; ++dt) {
            const int d = 32 * dt + col;
            Ctx[((size_t)b * SEQ + q) * HID + h * HDIM + d] =
                __float2bfloat16(O[dt][r] * inv);
        }
    }
}

// ---------------------------------------------------------------------------
// Kernel 3: output projection MFMA + bias + residual -> Resid fp32.
// grid (6, 64), block 256. Same 2-phase gload_lds structure as qkv.
// ---------------------------------------------------------------------------
__global__ __launch_bounds__(256) void out_mfma_kernel(
    const __hip_bfloat16* __restrict__ Cb, const __hip_bfloat16* __restrict__ Wto,
    const float* __restrict__ bo, const float* __restrict__ X,
    float* __restrict__ Resid)
{
    const int n0 = blockIdx.x * 128;
    const int m0 = blockIdx.y * 128;

    const int t    = threadIdx.x;
    const int w    = t >> 6;
    const int lane = t & 63;
    const int col  = lane & 31;
    const int g    = lane >> 5;
    const int wm   = w & 1;
    const int wn   = w >> 1;

    __shared__ __hip_bfloat16 smem[4 * 128 * 64];   // A dbuf | B dbuf = 64 KiB
    __hip_bfloat16 (*Asb)[128][64] = (__hip_bfloat16(*)[128][64])smem;
    __hip_bfloat16 (*Bsb)[128][64] = (__hip_bfloat16(*)[128][64])(smem + 2 * 128 * 64);

    const int r0  = t >> 3;
    const int csw = (((t & 7) ^ (r0 & 7)) << 3);

    const __hip_bfloat16* __restrict__ Am = Cb  + (size_t)m0 * HID;
    const __hip_bfloat16* __restrict__ Bn = Wto + (size_t)n0 * HID;

    f32x16 acc[2][2];
#pragma unroll
    for (int mt = 0; mt < 2; ++mt)
#pragma unroll
        for (int nt = 0; nt < 2; ++nt)
#pragma unroll
            for (int r = 0; r < 16; ++r) acc[mt][nt][r] = 0.f;

    GSTAGE(Asb, Bsb, 0, Am, Bn, 0);
    __syncthreads();
    for (int k0 = 0; k0 < HID; k0 += 128) {
        GSTAGE(Asb, Bsb, 1, Am, Bn, k0 + 64);
        GTILE(Asb, Bsb, 0);
        __syncthreads();
        if (k0 + 128 < HID) GSTAGE(Asb, Bsb, 0, Am, Bn, k0 + 128);
        GTILE(Asb, Bsb, 1);
        __syncthreads();
    }

#pragma unroll
    for (int mt = 0; mt < 2; ++mt)
#pragma unroll
        for (int nt = 0; nt < 2; ++nt) {
            const int n = n0 + 64 * wn + 32 * nt + col;
            const float bsv = bo[n];
#pragma unroll
            for (int r = 0; r < 16; ++r) {
                const int m = m0 + 64 * wm + 32 * mt + (r & 3) + 8 * (r >> 2) + 4 * g;
                Resid[(size_t)m * HID + n] = acc[mt][nt][r] + bsv + X[(size_t)m * HID + n];
            }
        }
}

// ---------------------------------------------------------------------------
// Kernel 4: LayerNorm.
// ---------------------------------------------------------------------------
__global__ __launch_bounds__(256) void ln_kernel(
    const float* __restrict__ Rin, const float* __restrict__ gamma,
    const float* __restrict__ beta, float* __restrict__ Out)
{
    const int row = blockIdx.x;
    const int t   = threadIdx.x;
    const float* __restrict__ x = Rin + (size_t)row * HID;

    const float v0 = x[t];
    const float v1 = x[t + 256];
    const float v2 = x[t + 512];
    float s  = v0 + v1 + v2;
    float s2 = v0 * v0 + v1 * v1 + v2 * v2;
#pragma unroll
    for (int off = 32; off; off >>= 1) {
        s  += __shfl_xor(s,  off, 64);
        s2 += __shfl_xor(s2, off, 64);
    }
    __shared__ float rs[4], rs2[4];
    const int w = t >> 6, lane = t & 63;
    if (lane == 0) { rs[w] = s; rs2[w] = s2; }
    __syncthreads();
    const float tot  = rs[0] + rs[1] + rs[2] + rs[3];
    const float tot2 = rs2[0] + rs2[1] + rs2[2] + rs2[3];
    const float mu   = tot * (1.0f / HID);
    const float var  = tot2 * (1.0f / HID) - mu * mu;
    const float rsig = rsqrtf(var + 1e-5f);

    float* __restrict__ y = Out + (size_t)row * HID;
    y[t]       = (v0 - mu) * rsig * gamma[t]       + beta[t];
    y[t + 256] = (v1 - mu) * rsig * gamma[t + 256] + beta[t + 256];
    y[t + 512] = (v2 - mu) * rsig * gamma[t + 512] + beta[t + 512];
}

// ---------------------------------------------------------------------------
extern "C" void kernel_launch(void* const* d_in, const int* in_sizes, int n_in,
                              void* d_out, int out_size, void* d_ws, size_t ws_size,
                              hipStream_t stream)
{
    const float* X     = (const float*)d_in[0];
    const float* mask  = (const float*)d_in[1];
    const float* Wq    = (const float*)d_in[2];
    const float* bq    = (const float*)d_in[3];
    const float* Wk    = (const float*)d_in[4];
    const float* bk    = (const float*)d_in[5];
    const float* Wv    = (const float*)d_in[6];
    const float* bv    = (const float*)d_in[7];
    const float* Wo    = (const float*)d_in[8];
    const float* bo    = (const float*)d_in[9];
    const float* gamma = (const float*)d_in[10];
    const float* beta  = (const float*)d_in[11];
    float* out = (float*)d_out;

    const size_t N = (size_t)MTOT * HID;        // 6,291,456 elements
    const size_t WTE = (size_t)4 * HID * HID;

    char* p = (char*)d_ws;
    __hip_bfloat16* Xb  = (__hip_bfloat16*)p;  p += 2 * N;
    __hip_bfloat16* Wt  = (__hip_bfloat16*)p;  p += 2 * WTE;
    __hip_bfloat16* Qw  = (__hip_bfloat16*)p;  p += 2 * N;
    __hip_bfloat16* Kw  = (__hip_bfloat16*)p;  p += 2 * N;
    __hip_bfloat16* Vtw = (__hip_bfloat16*)p;  p += 2 * N;

    __hip_bfloat16* Ctxb = Xb;      // Xb dead after qkv; attn writes Ctx here
    float* Rd = (float*)Kw;         // Kw+Vtw dead after attn: exactly N fp32

    cast_x_kernel<<<(int)(N / 2048), 256, 0, stream>>>(X, Xb);
    pack_w_kernel<<<dim3(12, 12, 4), 256, 0, stream>>>(Wq, Wk, Wv, Wo, Wt);
    qkv_mfma_kernel<<<dim3(18, MTOT / 128), 256, 0, stream>>>(
        Xb, Wt, bq, bk, bv, Qw, Kw, Vtw);
    attn_kernel<<<dim3(SEQ / 128, BB * NHEADS), 256, 0, stream>>>(
        Qw, Kw, Vtw, mask, Ctxb);
    out_mfma_kernel<<<dim3(6, MTOT / 128), 256, 0, stream>>>(
        Ctxb, Wt + (size_t)2304 * HID, bo, X, Rd);
    ln_kernel<<<MTOT, 256, 0, stream>>>(Rd, gamma, beta, out);
}